// Round 10
// baseline (346.193 us; speedup 1.0000x reference)
//
#include <hip/hip_runtime.h>
#include <stdint.h>

// BiMultiHeadAttention (GLIP bi-attention), MI355X bf16 MFMA pipeline.
// B=32 VN=576 LN=128 E=1024 H=16 D=64, V_DIM=1024 L_DIM=768, SCALE=0.25.

typedef unsigned short bfu;   // bf16 storage
typedef __attribute__((ext_vector_type(4))) float f32x4;
typedef __attribute__((ext_vector_type(8))) short short8;
typedef __attribute__((ext_vector_type(4))) unsigned short u16x4;

#define MFMA16(a,b,c) __builtin_amdgcn_mfma_f32_16x16x32_bf16((a),(b),(c),0,0,0)
#define SCALE_QK 0.25f

__device__ __forceinline__ unsigned short f2bf(float x) {
  unsigned int u = __float_as_uint(x);
  u += 0x7fffu + ((u >> 16) & 1u);   // round-to-nearest-even
  return (unsigned short)(u >> 16);
}

__device__ __forceinline__ void gload_lds16(const void* g, void* l) {
  __builtin_amdgcn_global_load_lds(
      reinterpret_cast<__attribute__((address_space(1))) void*>(
          reinterpret_cast<uintptr_t>(g)),
      reinterpret_cast<__attribute__((address_space(3))) void*>(
          (uint32_t)reinterpret_cast<uintptr_t>(l)),
      16, 0, 0);
}

// ---------------------------------------------------------------- converts
__global__ void cvt_f32_bf16(const float* __restrict__ x, bfu* __restrict__ y, int n4) {
  for (int i = blockIdx.x * blockDim.x + threadIdx.x; i < n4; i += gridDim.x * blockDim.x) {
    const float4 f = *reinterpret_cast<const float4*>(x + (size_t)i * 4);
    u16x4 o;
    o[0] = f2bf(f.x); o[1] = f2bf(f.y); o[2] = f2bf(f.z); o[3] = f2bf(f.w);
    *reinterpret_cast<u16x4*>(y + (size_t)i * 4) = o;
  }
}

struct CvtArgs {
  const float* src[7];
  bfu* dst[7];
  int n4[7];
};

__global__ void cvt_multi(CvtArgs a) {
  const int s = blockIdx.y;
  const float* __restrict__ x = a.src[s];
  bfu* __restrict__ y = a.dst[s];
  const int n4 = a.n4[s];
  for (int i = blockIdx.x * blockDim.x + threadIdx.x; i < n4; i += gridDim.x * blockDim.x) {
    const float4 f = *reinterpret_cast<const float4*>(x + (size_t)i * 4);
    u16x4 o;
    o[0] = f2bf(f.x); o[1] = f2bf(f.y); o[2] = f2bf(f.z); o[3] = f2bf(f.w);
    *reinterpret_cast<u16x4*>(y + (size_t)i * 4) = o;
  }
}

// ---------------------------------------------------------------- GEMM 128-tile (m97 structure) — R5 version
__global__ __launch_bounds__(256) void gemm_bt(
    const bfu* __restrict__ A, const bfu* __restrict__ W, const float* __restrict__ bias,
    bfu* __restrict__ Cb, float* __restrict__ Cf, bfu* __restrict__ Ct, int R, int colsplit,
    int ldc, int M, int N, int K, int nbn)
{
  __shared__ bfu As[128 * 32];
  __shared__ bfu Bs[128 * 32];
  const int nbm = M >> 7;
  const int bid = blockIdx.x;
  int bm, bn;
  if ((nbm & 7) == 0) {             // bijective XCD-aware swizzle
    const int xcd = bid & 7, j = bid >> 3;
    const int jm = j / nbn;
    bm = xcd * (nbm >> 3) + jm;
    bn = j - jm * nbn;
  } else { bm = bid / nbn; bn = bid - (bid / nbn) * nbn; }

  const int t = threadIdx.x, l = t & 63, w = t >> 6;
  const int g = l >> 4, c = l & 15;
  const int wr = (w >> 1) * 64, wc = (w & 1) * 64;

  f32x4 zero = {0.f, 0.f, 0.f, 0.f};
  f32x4 acc[4][4];
  for (int m = 0; m < 4; ++m)
    for (int n = 0; n < 4; ++n) acc[m][n] = zero;

  const int rowA = l >> 2;
  const int kb   = (l & 3) * 16;

  for (int k0 = 0; k0 < K; k0 += 32) {
#pragma unroll
    for (int i = 0; i < 2; ++i) {
      int chunk = w * 2 + i;
      int r = chunk * 16 + rowA;
      const char* ga = (const char*)(A + (size_t)(bm * 128 + r) * K + k0) + kb;
      const char* gb = (const char*)(W + (size_t)(bn * 128 + r) * K + k0) + kb;
      gload_lds16(ga, (char*)As + chunk * 1024);
      gload_lds16(gb, (char*)Bs + chunk * 1024);
    }
    __syncthreads();
    short8 a[4], bf[4];
#pragma unroll
    for (int m = 0; m < 4; ++m)
      a[m] = *reinterpret_cast<const short8*>(&As[(wr + m * 16 + c) * 32 + g * 8]);
#pragma unroll
    for (int n = 0; n < 4; ++n)
      bf[n] = *reinterpret_cast<const short8*>(&Bs[(wc + n * 16 + c) * 32 + g * 8]);
#pragma unroll
    for (int m = 0; m < 4; ++m)
#pragma unroll
      for (int n = 0; n < 4; ++n)
        acc[m][n] = MFMA16(a[m], bf[n], acc[m][n]);
    __syncthreads();
  }

#pragma unroll
  for (int n = 0; n < 4; ++n) {
    const int col = bn * 128 + wc + n * 16 + c;
    const float bs = bias[col];
    if (col >= colsplit) {
      const int colp = col - colsplit;
      const int hh = colp >> 6, dd = colp & 63;
#pragma unroll
      for (int m = 0; m < 4; ++m) {
        const int row0 = bm * 128 + wr + m * 16 + g * 4;
        const int bb = row0 / R, q0 = row0 - bb * R;
        u16x4 pk;
#pragma unroll
        for (int r = 0; r < 4; ++r) pk[r] = f2bf(acc[m][n][r] + bs);
        *reinterpret_cast<u16x4*>(Ct + ((size_t)(bb * 16 + hh) * 64 + dd) * R + q0) = pk;
      }
    } else {
#pragma unroll
      for (int m = 0; m < 4; ++m) {
        const int row0 = bm * 128 + wr + m * 16 + g * 4;
#pragma unroll
        for (int r = 0; r < 4; ++r) {
          float val = acc[m][n][r] + bs;
          size_t idx = (size_t)(row0 + r) * ldc + col;
          if (Cf) Cf[idx] = val;
          else    Cb[idx] = f2bf(val);
        }
      }
    }
  }
}

// ---------------------------------------------------------------- GEMM 256-tile, 8-phase schedule (R7 best)
template<int RT>
__global__ __launch_bounds__(512, 2) void gemm256(
    const bfu* __restrict__ A, const bfu* __restrict__ W, const float* __restrict__ bias,
    bfu* __restrict__ Cb, float* __restrict__ Cf, bfu* __restrict__ Ct, int colsplit,
    int ldc, int M, int N, int K, int nbn)
{
  __shared__ bfu lds[65536];          // 131072 B

  const int tid = threadIdx.x;
  const int w = tid >> 6, lane = tid & 63;
  const int g = lane >> 4, c = lane & 15;
  const int wr = w >> 2, wc = w & 3;

  const int nbm = M >> 8;
  int bm, bn;
  { const int xcd = blockIdx.x & 7, j = blockIdx.x >> 3;
    const int jm = j / nbn; bm = xcd * (nbm >> 3) + jm; bn = j - jm * nbn; }

  const int nt = K >> 6;

  const int srow8 = lane >> 3;                     // 0..7
  const int sslot = lane & 7;
  const int swzE  = ((sslot * 16) ^ (srow8 << 4)) >> 1;   // pre-swizzled elem offset in 64-elem row
  const bfu* srcA = A + (size_t)(bm * 256 + 8 * w + srow8) * K + swzE;
  const bfu* srcB = W + (size_t)(bn * 256 + 8 * w + srow8) * K + swzE;

#define AB(cur) (lds + (cur) * 32768)
#define BB(cur) (lds + (cur) * 32768 + 16384)
#define STAGE_A(cur, j, k0) gload_lds16(srcA + (size_t)(64 * (j)) * K + (k0), \
    (void*)(AB(cur) + (64 * (j) + 8 * w) * 64))
#define STAGE_B(cur, j, k0) gload_lds16(srcB + (size_t)(64 * (j)) * K + (k0), \
    (void*)(BB(cur) + (64 * (j) + 8 * w) * 64))

  short8 aF[4][2], bF[4][2];
  const int swzR = ((c & 7) << 3);                 // read-side swizzle (elems)

#define LDA(cur, mh) { _Pragma("unroll") for (int mi2 = 0; mi2 < 4; ++mi2) \
    _Pragma("unroll") for (int ks = 0; ks < 2; ++ks) \
      aF[mi2][ks] = *reinterpret_cast<const short8*>( \
        AB(cur) + (wr * 128 + ((mh) * 4 + mi2) * 16 + c) * 64 + ((ks * 32 + g * 8) ^ swzR)); }
#define LDB(cur, nh) { _Pragma("unroll") for (int ni2 = 0; ni2 < 2; ++ni2) \
    _Pragma("unroll") for (int ks = 0; ks < 2; ++ks) \
      bF[(nh) * 2 + ni2][ks] = *reinterpret_cast<const short8*>( \
        BB(cur) + (wc * 64 + ((nh) * 2 + ni2) * 16 + c) * 64 + ((ks * 32 + g * 8) ^ swzR)); }

  f32x4 acc[8][4];
  const f32x4 zero = {0.f, 0.f, 0.f, 0.f};
#pragma unroll
  for (int mi = 0; mi < 8; ++mi)
#pragma unroll
    for (int ni = 0; ni < 4; ++ni) acc[mi][ni] = zero;

#define PH_MFMA(mh, nh) { __builtin_amdgcn_s_setprio(1); \
    _Pragma("unroll") for (int mi2 = 0; mi2 < 4; ++mi2) \
    _Pragma("unroll") for (int ni2 = 0; ni2 < 2; ++ni2) \
    _Pragma("unroll") for (int ks = 0; ks < 2; ++ks) \
      acc[(mh) * 4 + mi2][(nh) * 2 + ni2] = \
        MFMA16(aF[mi2][ks], bF[(nh) * 2 + ni2][ks], acc[(mh) * 4 + mi2][(nh) * 2 + ni2]); \
    __builtin_amdgcn_s_setprio(0); }

  // ---- prologue: stage tile 0 fully
  STAGE_B(0, 0, 0); STAGE_B(0, 1, 0); STAGE_B(0, 2, 0); STAGE_B(0, 3, 0);
  STAGE_A(0, 0, 0); STAGE_A(0, 1, 0); STAGE_A(0, 2, 0); STAGE_A(0, 3, 0);
  asm volatile("s_waitcnt vmcnt(0)" ::: "memory");
  __builtin_amdgcn_s_barrier();

  int cur = 0;
  for (int t = 0; t < nt - 1; ++t) {
    const int k1 = (t + 1) * 64;
    LDB(cur, 0); LDA(cur, 0);
    STAGE_B(cur ^ 1, 0, k1); STAGE_B(cur ^ 1, 1, k1);
    __builtin_amdgcn_s_barrier();
    PH_MFMA(0, 0);
    __builtin_amdgcn_s_barrier();
    LDB(cur, 1);
    STAGE_B(cur ^ 1, 2, k1); STAGE_B(cur ^ 1, 3, k1);
    asm volatile("s_waitcnt vmcnt(4)" ::: "memory");
    __builtin_amdgcn_s_barrier();
    PH_MFMA(0, 1);
    __builtin_amdgcn_s_barrier();
    LDA(cur, 1);
    STAGE_A(cur ^ 1, 0, k1); STAGE_A(cur ^ 1, 2, k1);
    __builtin_amdgcn_s_barrier();
    PH_MFMA(1, 0);
    __builtin_amdgcn_s_barrier();
    STAGE_A(cur ^ 1, 1, k1); STAGE_A(cur ^ 1, 3, k1);
    asm volatile("s_waitcnt vmcnt(2)" ::: "memory");
    __builtin_amdgcn_s_barrier();
    PH_MFMA(1, 1);
    __builtin_amdgcn_s_barrier();
    cur ^= 1;
  }
  LDB(cur, 0); LDA(cur, 0);
  __builtin_amdgcn_s_barrier();
  PH_MFMA(0, 0);
  __builtin_amdgcn_s_barrier();
  LDB(cur, 1);
  asm volatile("s_waitcnt vmcnt(0)" ::: "memory");
  __builtin_amdgcn_s_barrier();
  PH_MFMA(0, 1);
  __builtin_amdgcn_s_barrier();
  LDA(cur, 1);
  PH_MFMA(1, 0);
  PH_MFMA(1, 1);

  // ---- epilogue (bf16 paths bounce via per-wave region in buf0)
  short* bw = (short*)lds + w * 2176;
  const bool isCt = (RT > 0) && (bn * 256 >= colsplit);

  if (isCt) {
    const int RTl = (RT > 0 ? RT : 1);
#pragma unroll
    for (int ni = 0; ni < 4; ++ni) {
      const float bs = bias[bn * 256 + wc * 64 + ni * 16 + c];
#pragma unroll
      for (int mi = 0; mi < 8; ++mi) {
        u16x4 pk;
#pragma unroll
        for (int r = 0; r < 4; ++r) pk[r] = f2bf(acc[mi][ni][r] + bs);
        *reinterpret_cast<u16x4*>(&bw[c * 136 + mi * 16 + g * 4]) = pk;
      }
#pragma unroll
      for (int half = 0; half < 2; ++half)
#pragma unroll
        for (int qh = 0; qh < 2; ++qh) {
          const int dd = (lane >> 3) + half * 8;
          const int ql = (lane & 7) * 8 + qh * 64;
          short8 vx = *reinterpret_cast<const short8*>(&bw[dd * 136 + ql]);
          const int colp = bn * 256 + wc * 64 + ni * 16 + dd - colsplit;
          const int hh = colp >> 6, dl = colp & 63;
          const int qg = bm * 256 + wr * 128 + ql;
          const int bb = qg / RTl, q0 = qg - bb * RTl;
          *reinterpret_cast<short8*>(Ct + ((size_t)(bb * 16 + hh) * 64 + dl) * RTl + q0) = vx;
        }
    }
  } else if (Cf) {
#pragma unroll
    for (int ni = 0; ni < 4; ++ni) {
      const int col = bn * 256 + wc * 64 + ni * 16 + c;
      const float bs = bias[col];
#pragma unroll
      for (int mi = 0; mi < 8; ++mi) {
        const int row0 = bm * 256 + wr * 128 + mi * 16 + g * 4;
#pragma unroll
        for (int r = 0; r < 4; ++r)
          Cf[(size_t)(row0 + r) * ldc + col] = acc[mi][ni][r] + bs;
      }
    }
  } else {
    float bs4[4];
#pragma unroll
    for (int ni = 0; ni < 4; ++ni) bs4[ni] = bias[bn * 256 + wc * 64 + ni * 16 + c];
#pragma unroll
    for (int mi = 0; mi < 8; ++mi) {
#pragma unroll
      for (int ni = 0; ni < 4; ++ni)
#pragma unroll
        for (int r = 0; r < 4; ++r)
          bw[(g * 4 + r) * 72 + ni * 16 + c] = (short)f2bf(acc[mi][ni][r] + bs4[ni]);
#pragma unroll
      for (int half = 0; half < 2; ++half) {
        const int rr = (lane >> 3) + half * 8;
        const int cc2 = (lane & 7) * 8;
        short8 vx = *reinterpret_cast<const short8*>(&bw[rr * 72 + cc2]);
        const int grow = bm * 256 + wr * 128 + mi * 16 + rr;
        *reinterpret_cast<short8*>(Cb + (size_t)grow * ldc + bn * 256 + wc * 64 + cc2) = vx;
      }
    }
  }
#undef AB
#undef BB
#undef STAGE_A
#undef STAGE_B
#undef LDA
#undef LDB
#undef PH_MFMA
}

// ---------------------------------------------------------------- GEMM 256x128-tile, 8-phase (f32 out only)
// BM=256, BN=128, BK=64, 512 thr (8 waves: wr=w>>2 over 128 rows, wc=w&3 over 32 cols).
// LDS 96 KiB: 2 bufs x (A 32KB + B 16KB). Same zero-conflict 128B-row XOR swizzle as gemm256.
// 6 staging instrs/tile: B0,B1@p0, A0,A2@p1, A1,A3@p2; vmcnt(4)@p1, vmcnt(2)@p3 (never 0).
__global__ __launch_bounds__(512, 2) void gemm256n(
    const bfu* __restrict__ A, const bfu* __restrict__ W, const float* __restrict__ bias,
    float* __restrict__ Cf, int ldc, int M, int N, int K, int nbn)
{
  __shared__ bfu lds[49152];          // 2 x 24576 elems = 96 KiB

  const int tid = threadIdx.x;
  const int w = tid >> 6, lane = tid & 63;
  const int g = lane >> 4, c = lane & 15;
  const int wr = w >> 2, wc = w & 3;

  const int nbm = M >> 8;
  int bm, bn;
  { const int xcd = blockIdx.x & 7, j = blockIdx.x >> 3;
    const int jm = j / nbn; bm = xcd * (nbm >> 3) + jm; bn = j - jm * nbn; }

  const int nt = K >> 6;

  const int srow8 = lane >> 3;
  const int sslot = lane & 7;
  const int swzE  = ((sslot * 16) ^ (srow8 << 4)) >> 1;
  const bfu* srcA = A + (size_t)(bm * 256 + 8 * w + srow8) * K + swzE;
  const bfu* srcB = W + (size_t)(bn * 128 + 8 * w + srow8) * K + swzE;

#define AB(cur) (lds + (cur) * 24576)
#define BB(cur) (lds + (cur) * 24576 + 16384)
#define STAGE_A(cur, j, k0) gload_lds16(srcA + (size_t)(64 * (j)) * K + (k0), \
    (void*)(AB(cur) + (64 * (j) + 8 * w) * 64))
#define STAGE_B(cur, j, k0) gload_lds16(srcB + (size_t)(64 * (j)) * K + (k0), \
    (void*)(BB(cur) + (64 * (j) + 8 * w) * 64))

  short8 aF[4][2], bF[2][2];
  const int swzR = ((c & 7) << 3);

  // LDA(mh): m-tiles mh*4+mi2, rows wr*128 + mh*64 + mi2*16 + c  (chunk 2wr+mh)
#define LDA(cur, mh) { _Pragma("unroll") for (int mi2 = 0; mi2 < 4; ++mi2) \
    _Pragma("unroll") for (int ks = 0; ks < 2; ++ks) \
      aF[mi2][ks] = *reinterpret_cast<const short8*>( \
        AB(cur) + (wr * 128 + (mh) * 64 + mi2 * 16 + c) * 64 + ((ks * 32 + g * 8) ^ swzR)); }
  // LDB(nh): B row (=C col) wc*32 + nh*16 + c  (chunk wc>>1, both nh)
#define LDB(cur, nh) { _Pragma("unroll") for (int ks = 0; ks < 2; ++ks) \
      bF[nh][ks] = *reinterpret_cast<const short8*>( \
        BB(cur) + (wc * 32 + (nh) * 16 + c) * 64 + ((ks * 32 + g * 8) ^ swzR)); }

  f32x4 acc[8][2];
  const f32x4 zero = {0.f, 0.f, 0.f, 0.f};
#pragma unroll
  for (int mi = 0; mi < 8; ++mi) { acc[mi][0] = zero; acc[mi][1] = zero; }

#define PH_MFMA(mh, nh) { __builtin_amdgcn_s_setprio(1); \
    _Pragma("unroll") for (int mi2 = 0; mi2 < 4; ++mi2) \
    _Pragma("unroll") for (int ks = 0; ks < 2; ++ks) \
      acc[(mh) * 4 + mi2][nh] = MFMA16(aF[mi2][ks], bF[nh][ks], acc[(mh) * 4 + mi2][nh]); \
    __builtin_amdgcn_s_setprio(0); }

  // ---- prologue: stage tile 0 (6 instrs)
  STAGE_B(0, 0, 0); STAGE_B(0, 1, 0);
  STAGE_A(0, 0, 0); STAGE_A(0, 1, 0); STAGE_A(0, 2, 0); STAGE_A(0, 3, 0);
  asm volatile("s_waitcnt vmcnt(0)" ::: "memory");
  __builtin_amdgcn_s_barrier();

  int cur = 0;
  for (int t = 0; t < nt - 1; ++t) {
    const int k1 = (t + 1) * 64;
    // p0
    LDB(cur, 0); LDA(cur, 0);
    STAGE_B(cur ^ 1, 0, k1); STAGE_B(cur ^ 1, 1, k1);
    __builtin_amdgcn_s_barrier();
    PH_MFMA(0, 0);
    __builtin_amdgcn_s_barrier();
    // p1
    LDB(cur, 1);
    STAGE_A(cur ^ 1, 0, k1); STAGE_A(cur ^ 1, 2, k1);
    asm volatile("s_waitcnt vmcnt(4)" ::: "memory");   // this tile's A1,A3 landed
    __builtin_amdgcn_s_barrier();
    PH_MFMA(0, 1);
    __builtin_amdgcn_s_barrier();
    // p2
    LDA(cur, 1);
    STAGE_A(cur ^ 1, 1, k1); STAGE_A(cur ^ 1, 3, k1);
    __builtin_amdgcn_s_barrier();
    PH_MFMA(1, 0);
    __builtin_amdgcn_s_barrier();
    // p3
    asm volatile("s_waitcnt vmcnt(2)" ::: "memory");   // next tile ready except A1,A3
    __builtin_amdgcn_s_barrier();
    PH_MFMA(1, 1);
    __builtin_amdgcn_s_barrier();
    cur ^= 1;
  }
  // ---- last tile
  LDB(cur, 0); LDA(cur, 0);
  __builtin_amdgcn_s_barrier();
  PH_MFMA(0, 0);
  __builtin_amdgcn_s_barrier();
  LDB(cur, 1);
  asm volatile("s_waitcnt vmcnt(0)" ::: "memory");
  __builtin_amdgcn_s_barrier();
  PH_MFMA(0, 1);
  __builtin_amdgcn_s_barrier();
  LDA(cur, 1);
  PH_MFMA(1, 0);
  PH_MFMA(1, 1);

  // ---- epilogue: f32 row-major (64-B segments per instruction)
#pragma unroll
  for (int ni = 0; ni < 2; ++ni) {
    const int col = bn * 128 + wc * 32 + ni * 16 + c;
    const float bs = bias[col];
#pragma unroll
    for (int mi = 0; mi < 8; ++mi) {
      const int row0 = bm * 256 + wr * 128 + mi * 16 + g * 4;
#pragma unroll
      for (int r = 0; r < 4; ++r)
        Cf[(size_t)(row0 + r) * ldc + col] = acc[mi][ni][r] + bs;
    }
  }
#undef AB
#undef BB
#undef STAGE_A
#undef STAGE_B
#undef LDA
#undef LDB
#undef PH_MFMA
}

// ---------------------------------------------------------------- swizzled per-wave P-tile offsets
__device__ __forceinline__ int pvt_off(int q, int kbyte) { return q * 256 + (kbyte ^ ((q & 7) << 4)); }

// ---------------------------------------------------------------- attention stage A: xv + P^T + colsum partials
__global__ __launch_bounds__(256) void attn_xv(
    const bfu* __restrict__ Q, const bfu* __restrict__ Kl,
    const bfu* __restrict__ LVt, const float* __restrict__ mask,
    bfu* __restrict__ xv, bfu* __restrict__ PT, float* __restrict__ colpart)
{
  __shared__ short Ks[128 * 64];      // 16 KB, swizzled
  __shared__ short LVs[64 * 128];     // 16 KB, swizzled within 128B half-rows
  __shared__ short PvT[4][2048];      // per-wave 16x128 P tile; reused as bounce buf

  const int blk = blockIdx.x;
  const int bh = blk & 511, qc = blk >> 9;
  const int b = bh >> 4, h = bh & 15;
  const int t = threadIdx.x, l = t & 63, w = t >> 6;
  const int g = l >> 4, c = l & 15;
  const int qt = qc * 4 + w;

  const bfu* Qp  = Q   + ((size_t)b * 576 * 1024 + h * 64);
  const bfu* Kp  = Kl  + ((size_t)b * 128 * 1024 + h * 64);
  const bfu* LVp = LVt + (size_t)bh * 64 * 128;
  const f32x4 zero = {0.f, 0.f, 0.f, 0.f};

  {
    const int kr = l >> 3;
    const bfu* sK = Kp + (size_t)(w * 8 + kr) * 1024 + (((l & 7) ^ kr) * 8);
#pragma unroll
    for (int i = 0; i < 4; ++i)
      gload_lds16(sK + (size_t)(i * 32) * 1024, (void*)&Ks[(i * 32 + w * 8) * 64]);
    const int lr = l >> 4;
    const int key = (w * 4 + lr) & 7;
    const bfu* sLV = LVp + (size_t)(w * 4 + lr) * 128 + ((l >> 3) & 1) * 64 + (((l & 7) ^ key) * 8);
#pragma unroll
    for (int i = 0; i < 4; ++i)
      gload_lds16(sLV + (size_t)(i * 16) * 128, (void*)&LVs[(i * 16 + w * 4) * 128]);
  }
  float mk[8];
#pragma unroll
  for (int kt = 0; kt < 8; ++kt) mk[kt] = mask[kt * 16 + c];
  __syncthreads();

  f32x4 sacc[8];
#pragma unroll
  for (int kt = 0; kt < 8; ++kt) sacc[kt] = zero;
  __builtin_amdgcn_s_setprio(1);
#pragma unroll
  for (int kk = 0; kk < 2; ++kk) {
    short8 aq = *reinterpret_cast<const short8*>(Qp + (size_t)(qt * 16 + c) * 1024 + kk * 32 + g * 8);
#pragma unroll
    for (int kt = 0; kt < 8; ++kt) {
      short8 bk = *reinterpret_cast<const short8*>(
          &Ks[(kt * 16 + c) * 64 + (((kk * 4 + g) ^ (c & 7)) * 8)]);
      sacc[kt] = MFMA16(aq, bk, sacc[kt]);
    }
  }
  __builtin_amdgcn_s_setprio(0);

  char* myPv = (char*)&PvT[w][0];
  float rs[4] = {0, 0, 0, 0};
  float colacc[8];
#pragma unroll
  for (int kt = 0; kt < 8; ++kt) {
    u16x4 pk;
    float ca = 0.f;
#pragma unroll
    for (int r = 0; r < 4; ++r) {
      float Ev = __expf(fmaf(sacc[kt][r], SCALE_QK, mk[kt]));
      rs[r] += Ev;
      ca += Ev;
      pk[r] = f2bf(Ev);
      *reinterpret_cast<unsigned short*>(myPv + pvt_off(g * 4 + r, 2 * (kt * 16 + c))) = pk[r];
    }
    colacc[kt] = ca;
    *reinterpret_cast<u16x4*>(PT + ((size_t)bh * 128 + kt * 16 + c) * 576 + qt * 16 + g * 4) = pk;
  }
#pragma unroll
  for (int r = 0; r < 4; ++r) {
    rs[r] += __shfl_xor(rs[r], 1);
    rs[r] += __shfl_xor(rs[r], 2);
    rs[r] += __shfl_xor(rs[r], 4);
    rs[r] += __shfl_xor(rs[r], 8);
  }

  short8 av[4];
#pragma unroll
  for (int kc = 0; kc < 4; ++kc)
    av[kc] = *reinterpret_cast<const short8*>(myPv + pvt_off(c, kc * 64 + g * 16));
  f32x4 oxv[4];
#pragma unroll
  for (int dt = 0; dt < 4; ++dt) oxv[dt] = zero;
  __builtin_amdgcn_s_setprio(1);
#pragma unroll
  for (int dt = 0; dt < 4; ++dt)
#pragma unroll
    for (int kc = 0; kc < 4; ++kc) {
      short8 bv = *reinterpret_cast<const short8*>(
          &LVs[(dt * 16 + c) * 128 + (kc >> 1) * 64 + ((((kc & 1) * 4 + g) ^ (c & 7)) * 8)]);
      oxv[dt] = MFMA16(av[kc], bv, oxv[dt]);
    }
  __builtin_amdgcn_s_setprio(0);
#pragma unroll
  for (int r = 0; r < 4; ++r) rs[r] = 1.0f / rs[r];

  short* bw = (short*)&PvT[w][0];
#pragma unroll
  for (int dt = 0; dt < 4; ++dt)
#pragma unroll
    for (int r = 0; r < 4; ++r)
      bw[(g * 4 + r) * 72 + dt * 16 + c] = (short)f2bf(oxv[dt][r] * rs[r]);
#pragma unroll
  for (int half = 0; half < 2; ++half) {
    const int rr = (l >> 3) + half * 8;
    const int cc = (l & 7) * 8;
    short8 vx = *reinterpret_cast<const short8*>(&bw[rr * 72 + cc]);
    *reinterpret_cast<short8*>(xv + (size_t)(b * 576 + qt * 16 + rr) * 1024 + h * 64 + cc) = vx;
  }

#pragma unroll
  for (int kt = 0; kt < 8; ++kt) {
    colacc[kt] += __shfl_xor(colacc[kt], 16);
    colacc[kt] += __shfl_xor(colacc[kt], 32);
  }
  if (g == 0) {
#pragma unroll
    for (int kt = 0; kt < 8; ++kt)
      colpart[(size_t)(bh * 36 + qt) * 128 + kt * 16 + c] = colacc[kt];
  }
}

// ---------------------------------------------------------------- attention stage B: xl = P^T @ VV / colsum
__global__ __launch_bounds__(64) void attn_xl(
    const bfu* __restrict__ PT, const bfu* __restrict__ VVt,
    const float* __restrict__ colpart, bfu* __restrict__ xl)
{
  __shared__ short XL[1168];

  const int blk = blockIdx.x;
  const int bh = blk & 511, kt = blk >> 9;
  const int b = bh >> 4, h = bh & 15;
  const int l = threadIdx.x;
  const int g = l >> 4, c = l & 15;

  const bfu* PTb  = PT  + ((size_t)bh * 128 + kt * 16 + c) * 576;
  const bfu* VVp  = VVt + (size_t)bh * 64 * 576;
  const f32x4 zero = {0.f, 0.f, 0.f, 0.f};

  float s = 0.f;
  const float* cp = colpart + (size_t)bh * 36 * 128 + kt * 16 + c;
#pragma unroll
  for (int qc = 0; qc < 36; ++qc) s += cp[qc * 128];
  float sinv = 1.0f / s;
  float ci[4];
#pragma unroll
  for (int r = 0; r < 4; ++r) ci[r] = __shfl(sinv, g * 4 + r);

  f32x4 acc[4];
#pragma unroll
  for (int dt = 0; dt < 4; ++dt) acc[dt] = zero;

  __builtin_amdgcn_s_setprio(1);
  for (int p = 0; p < 18; ++p) {
    short8 ap = *reinterpret_cast<const short8*>(PTb + p * 32 + g * 8);
#pragma unroll
    for (int dt = 0; dt < 4; ++dt) {
      short8 bv = *reinterpret_cast<const short8*>(VVp + (size_t)(dt * 16 + c) * 576 + p * 32 + g * 8);
      acc[dt] = MFMA16(ap, bv, acc[dt]);
    }
  }
  __builtin_amdgcn_s_setprio(0);

#pragma unroll
  for (int dt = 0; dt < 4; ++dt)
#pragma unroll
    for (int r = 0; r < 4; ++r)
      XL[(g * 4 + r) * 72 + dt * 16 + c] = (short)f2bf(acc[dt][r] * ci[r]);
#pragma unroll
  for (int half = 0; half < 2; ++half) {
    const int rr = (l >> 3) + half * 8;
    const int cc = (l & 7) * 8;
    short8 vx = *reinterpret_cast<const short8*>(&XL[rr * 72 + cc]);
    *reinterpret_cast<short8*>(xl + (size_t)(b * 128 + kt * 16 + rr) * 1024 + h * 64 + cc) = vx;
  }
}

// ---------------------------------------------------------------- host
static inline int cvt_grid(int n4) {
  int g = (n4 + 255) / 256;
  return g > 4096 ? 4096 : g;
}

extern "C" void kernel_launch(void* const* d_in, const int* in_sizes, int n_in,
                              void* d_out, int out_size, void* d_ws, size_t ws_size,
                              hipStream_t stream)
{
  const float* v    = (const float*)d_in[0];
  const float* lx   = (const float*)d_in[1];
  const float* mask = (const float*)d_in[2];
  const float* Wvq  = (const float*)d_in[3];
  const float* bvq  = (const float*)d_in[4];
  const float* Wlk  = (const float*)d_in[5];
  const float* blk  = (const float*)d_in[6];
  const float* Wvv  = (const float*)d_in[7];
  const float* bvv  = (const float*)d_in[8];
  const float* Wlv  = (const float*)d_in[9];
  const float* blv  = (const float*)d_in[10];
  const float* Wvo  = (const float*)d_in[11];
  const float* bvo  = (const float*)d_in[12];
  const float* Wlo  = (const float*)d_in[13];
  const float* blo  = (const float*)d_in[14];

  float* out_xv = (float*)d_out;                       // 18432 x 1024
  float* out_xl = out_xv + (size_t)18432 * 1024;       // 4096 x 768

  bfu* ws   = (bfu*)d_ws;
  bfu* vb   = ws;                      // 18874368 (later aliased as xv bf16)
  bfu* lb   = vb   + 18874368;         // 3145728  (later aliased by colpart)
  bfu* wqv  = lb   + 3145728;          // 2097152  [Wvq ; Wvv] (2048x1024)
  bfu* wklv = wqv  + 2097152;          // 1572864  [Wlk ; Wlv] (2048x768)
  bfu* wvo  = wklv + 1572864;          // 1048576
  bfu* wlo  = wvo  + 1048576;          // 786432
  bfu* Qb   = wlo  + 786432;           // 18874368  [18432][1024] bf16
  bfu* VVt  = Qb   + 18874368;         // 18874368  [bh][64][576]
  bfu* Kb   = VVt  + 18874368;         // 4194304   [4096][1024] (later aliased as xl bf16)
  bfu* LVt  = Kb   + 4194304;          // 4194304   [bh][64][128]
  bfu* PT   = LVt  + 4194304;          // 37748736  [bh][128][576]
  float* biasqv = (float*)(PT + 37748736);   // 2048 f32  [bvq ; bvv]
  float* biaskl = biasqv + 2048;             // 2048 f32  [blk ; blv]
  float* colpart = (float*)lb;               // 512*36*128 f32, aliases lb/wqv (dead by then)

  // 1) converts + bias concat
  cvt_f32_bf16<<<cvt_grid(18874368 / 4), 256, 0, stream>>>(v, vb, 18874368 / 4);
  CvtArgs ca;
  ca.src[0] = lx;  ca.dst[0] = lb;             ca.n4[0] = 3145728 / 4;
  ca.src[1] = Wvq; ca.dst[1] = wqv;            ca.n4[1] = 1048576 / 4;
  ca.src[2] = Wvv; ca.dst[2] = wqv + 1048576;  ca.n4[2] = 1048576 / 4;
  ca.src[3] = Wlk; ca.dst[3] = wklv;           ca.n4[3] = 786432 / 4;
  ca.src[4] = Wlv; ca.dst[4] = wklv + 786432;  ca.n4[4] = 786432 / 4;
  ca.src[5] = Wvo; ca.dst[5] = wvo;            ca.n4[5] = 1048576 / 4;
  ca.src[6] = Wlo; ca.dst[6] = wlo;            ca.n4[6] = 786432 / 4;
  cvt_multi<<<dim3(1024, 7), 256, 0, stream>>>(ca);
  hipMemcpyAsync(biasqv,        bvq, 1024 * sizeof(float), hipMemcpyDeviceToDevice, stream);
  hipMemcpyAsync(biasqv + 1024, bvv, 1024 * sizeof(float), hipMemcpyDeviceToDevice, stream);
  hipMemcpyAsync(biaskl,        blk, 1024 * sizeof(float), hipMemcpyDeviceToDevice, stream);
  hipMemcpyAsync(biaskl + 1024, blv, 1024 * sizeof(float), hipMemcpyDeviceToDevice, stream);

  // 2) projections: QV on 8-phase 256-tile kernel; KL on the 128-tile kernel
  gemm256<576><<<72 * 8, 512, 0, stream>>>(vb, wqv, biasqv, Qb, nullptr, VVt, 1024, 1024,
                                           18432, 2048, 1024, 8);
  gemm_bt<<<32 * 16, 256, 0, stream>>>(lb, wklv, biaskl, Kb, nullptr, LVt, 128, 1024, 1024,
                                       4096, 2048, 768, 16);

  // 3) attention: 4-wave blocks with K/LV in LDS (xv -> vb alias, xl -> Kb alias)
  attn_xv<<<512 * 9, 256, 0, stream>>>(Qb, Kb, LVt, mask, vb, PT, colpart);
  attn_xl<<<512 * 8, 64, 0, stream>>>(PT, VVt, colpart, Kb);

  // 4) output GEMMs: out_xv on 256x128 8-phase kernel (576 blocks), out_xl on 128-tile
  gemm256n<<<72 * 8, 512, 0, stream>>>(vb, wvo, bvo, out_xv, 1024, 18432, 1024, 1024, 8);
  gemm_bt<<<32 * 6, 256, 0, stream>>>(Kb, wlo, blo, nullptr, out_xl, nullptr, 0, 768, 768,
                                      4096, 768, 1024, 6);
}

// Round 11
// 327.825 us; speedup vs baseline: 1.0560x; 1.0560x over previous
//
#include <hip/hip_runtime.h>
#include <stdint.h>

// BiMultiHeadAttention (GLIP bi-attention), MI355X bf16 MFMA pipeline.
// B=32 VN=576 LN=128 E=1024 H=16 D=64, V_DIM=1024 L_DIM=768, SCALE=0.25.

typedef unsigned short bfu;   // bf16 storage
typedef __attribute__((ext_vector_type(4))) float f32x4;
typedef __attribute__((ext_vector_type(8))) short short8;
typedef __attribute__((ext_vector_type(4))) unsigned short u16x4;

#define MFMA16(a,b,c) __builtin_amdgcn_mfma_f32_16x16x32_bf16((a),(b),(c),0,0,0)
#define SCALE_QK 0.25f

__device__ __forceinline__ unsigned short f2bf(float x) {
  unsigned int u = __float_as_uint(x);
  u += 0x7fffu + ((u >> 16) & 1u);   // round-to-nearest-even
  return (unsigned short)(u >> 16);
}

__device__ __forceinline__ void gload_lds16(const void* g, void* l) {
  __builtin_amdgcn_global_load_lds(
      reinterpret_cast<__attribute__((address_space(1))) void*>(
          reinterpret_cast<uintptr_t>(g)),
      reinterpret_cast<__attribute__((address_space(3))) void*>(
          (uint32_t)reinterpret_cast<uintptr_t>(l)),
      16, 0, 0);
}

// ---------------------------------------------------------------- converts
__global__ void cvt_f32_bf16(const float* __restrict__ x, bfu* __restrict__ y, int n4) {
  for (int i = blockIdx.x * blockDim.x + threadIdx.x; i < n4; i += gridDim.x * blockDim.x) {
    const float4 f = *reinterpret_cast<const float4*>(x + (size_t)i * 4);
    u16x4 o;
    o[0] = f2bf(f.x); o[1] = f2bf(f.y); o[2] = f2bf(f.z); o[3] = f2bf(f.w);
    *reinterpret_cast<u16x4*>(y + (size_t)i * 4) = o;
  }
}

struct CvtArgs {
  const float* src[7];
  bfu* dst[7];
  int n4[7];
};

__global__ void cvt_multi(CvtArgs a) {
  const int s = blockIdx.y;
  const float* __restrict__ x = a.src[s];
  bfu* __restrict__ y = a.dst[s];
  const int n4 = a.n4[s];
  for (int i = blockIdx.x * blockDim.x + threadIdx.x; i < n4; i += gridDim.x * blockDim.x) {
    const float4 f = *reinterpret_cast<const float4*>(x + (size_t)i * 4);
    u16x4 o;
    o[0] = f2bf(f.x); o[1] = f2bf(f.y); o[2] = f2bf(f.z); o[3] = f2bf(f.w);
    *reinterpret_cast<u16x4*>(y + (size_t)i * 4) = o;
  }
}

// ---------------------------------------------------------------- GEMM 128-tile (m97 structure) — R5 version
__global__ __launch_bounds__(256) void gemm_bt(
    const bfu* __restrict__ A, const bfu* __restrict__ W, const float* __restrict__ bias,
    bfu* __restrict__ Cb, float* __restrict__ Cf, bfu* __restrict__ Ct, int R, int colsplit,
    int ldc, int M, int N, int K, int nbn)
{
  __shared__ bfu As[128 * 32];
  __shared__ bfu Bs[128 * 32];
  const int nbm = M >> 7;
  const int bid = blockIdx.x;
  int bm, bn;
  if ((nbm & 7) == 0) {             // bijective XCD-aware swizzle
    const int xcd = bid & 7, j = bid >> 3;
    const int jm = j / nbn;
    bm = xcd * (nbm >> 3) + jm;
    bn = j - jm * nbn;
  } else { bm = bid / nbn; bn = bid - (bid / nbn) * nbn; }

  const int t = threadIdx.x, l = t & 63, w = t >> 6;
  const int g = l >> 4, c = l & 15;
  const int wr = (w >> 1) * 64, wc = (w & 1) * 64;

  f32x4 zero = {0.f, 0.f, 0.f, 0.f};
  f32x4 acc[4][4];
  for (int m = 0; m < 4; ++m)
    for (int n = 0; n < 4; ++n) acc[m][n] = zero;

  const int rowA = l >> 2;
  const int kb   = (l & 3) * 16;

  for (int k0 = 0; k0 < K; k0 += 32) {
#pragma unroll
    for (int i = 0; i < 2; ++i) {
      int chunk = w * 2 + i;
      int r = chunk * 16 + rowA;
      const char* ga = (const char*)(A + (size_t)(bm * 128 + r) * K + k0) + kb;
      const char* gb = (const char*)(W + (size_t)(bn * 128 + r) * K + k0) + kb;
      gload_lds16(ga, (char*)As + chunk * 1024);
      gload_lds16(gb, (char*)Bs + chunk * 1024);
    }
    __syncthreads();
    short8 a[4], bf[4];
#pragma unroll
    for (int m = 0; m < 4; ++m)
      a[m] = *reinterpret_cast<const short8*>(&As[(wr + m * 16 + c) * 32 + g * 8]);
#pragma unroll
    for (int n = 0; n < 4; ++n)
      bf[n] = *reinterpret_cast<const short8*>(&Bs[(wc + n * 16 + c) * 32 + g * 8]);
#pragma unroll
    for (int m = 0; m < 4; ++m)
#pragma unroll
      for (int n = 0; n < 4; ++n)
        acc[m][n] = MFMA16(a[m], bf[n], acc[m][n]);
    __syncthreads();
  }

#pragma unroll
  for (int n = 0; n < 4; ++n) {
    const int col = bn * 128 + wc + n * 16 + c;
    const float bs = bias[col];
    if (col >= colsplit) {
      const int colp = col - colsplit;
      const int hh = colp >> 6, dd = colp & 63;
#pragma unroll
      for (int m = 0; m < 4; ++m) {
        const int row0 = bm * 128 + wr + m * 16 + g * 4;
        const int bb = row0 / R, q0 = row0 - bb * R;
        u16x4 pk;
#pragma unroll
        for (int r = 0; r < 4; ++r) pk[r] = f2bf(acc[m][n][r] + bs);
        *reinterpret_cast<u16x4*>(Ct + ((size_t)(bb * 16 + hh) * 64 + dd) * R + q0) = pk;
      }
    } else {
#pragma unroll
      for (int m = 0; m < 4; ++m) {
        const int row0 = bm * 128 + wr + m * 16 + g * 4;
#pragma unroll
        for (int r = 0; r < 4; ++r) {
          float val = acc[m][n][r] + bs;
          size_t idx = (size_t)(row0 + r) * ldc + col;
          if (Cf) Cf[idx] = val;
          else    Cb[idx] = f2bf(val);
        }
      }
    }
  }
}

// ---------------------------------------------------------------- GEMM 192x256-tile, 8-phase schedule
// BM=192, BN=256, BK=64, 512 thr (8 waves: wr=w>>2 M-half of 96 rows, wc=w&3 N-quarter).
// Grid: (M/192)*(N/256) -- chosen so QV = 768 blocks (3 exact rounds), out_xv = 384 (1.5 rounds).
// LDS 112 KiB: 2 bufs x (A 24KB + B 32KB); 128B-row XOR swizzle (R7-verified, keys 48/96/144 ≡ 0 mod 8).
// wr=1 waves compute their m-tiles in REVERSED quadrant order so phase 0 only needs chunks A0+A2,
// phase 2 adds A1 -> staging leads >= 2 phases everywhere except L2-hot B2,B3 (1 phase).
// Staging order per tile (7 loads): B0,B1@p0; A0,A2@p1; B2,B3@p2; A1@p3. Waits: vmcnt(4)@p1,
// vmcnt(1)@p3 -- never 0 in the main loop.
template<int RT>
__global__ __launch_bounds__(512, 2) void gemm192(
    const bfu* __restrict__ A, const bfu* __restrict__ W, const float* __restrict__ bias,
    bfu* __restrict__ Cb, float* __restrict__ Cf, bfu* __restrict__ Ct, int colsplit,
    int ldc, int M, int N, int K, int nbn)
{
  __shared__ bfu lds[2 * 28672];      // 114688 B

  const int tid = threadIdx.x;
  const int w = tid >> 6, lane = tid & 63;
  const int g = lane >> 4, c = lane & 15;
  const int wr = w >> 2, wc = w & 3;
  const int rowb0 = wr ? 144 : 0;     // quadrant mh=0 row base (chunk A0 / A2)
  const int rowb1 = wr ? 96 : 48;     // quadrant mh=1 row base (needs A1)

  const int nbm = M / 192;
  int bm, bn;
  { const int xcd = blockIdx.x & 7, j = blockIdx.x >> 3;
    const int jm = j / nbn; bm = xcd * (nbm >> 3) + jm; bn = j - jm * nbn; }

  const int nt = K >> 6;

  const int srow8 = lane >> 3;                     // 0..7
  const int sslot = lane & 7;
  const int swzE  = ((sslot * 16) ^ (srow8 << 4)) >> 1;   // pre-swizzled elem offset
  const bfu* srcA = A + (size_t)(bm * 192 + 8 * w + srow8) * K + swzE;
  const bfu* srcB = W + (size_t)(bn * 256 + 8 * w + srow8) * K + swzE;

#define AB(cur) (lds + (cur) * 28672)
#define BB(cur) (lds + (cur) * 28672 + 12288)
#define STAGE_A(cur, j, k0) gload_lds16(srcA + (size_t)(64 * (j)) * K + (k0), \
    (void*)(AB(cur) + (64 * (j) + 8 * w) * 64))
#define STAGE_B(cur, j, k0) gload_lds16(srcB + (size_t)(64 * (j)) * K + (k0), \
    (void*)(BB(cur) + (64 * (j) + 8 * w) * 64))

  short8 aF[3][2], bF[4][2];
  const int swzR = ((c & 7) << 3);                 // read-side swizzle (elems)

#define LDA(cur, mh) { _Pragma("unroll") for (int mi2 = 0; mi2 < 3; ++mi2) \
    _Pragma("unroll") for (int ks = 0; ks < 2; ++ks) \
      aF[mi2][ks] = *reinterpret_cast<const short8*>( \
        AB(cur) + (((mh) ? rowb1 : rowb0) + mi2 * 16 + c) * 64 + ((ks * 32 + g * 8) ^ swzR)); }
#define LDB(cur, nh) { _Pragma("unroll") for (int ni2 = 0; ni2 < 2; ++ni2) \
    _Pragma("unroll") for (int ks = 0; ks < 2; ++ks) \
      bF[(nh) * 2 + ni2][ks] = *reinterpret_cast<const short8*>( \
        BB(cur) + (wc * 64 + (nh) * 32 + ni2 * 16 + c) * 64 + ((ks * 32 + g * 8) ^ swzR)); }

  f32x4 acc[6][4];
  const f32x4 zero = {0.f, 0.f, 0.f, 0.f};
#pragma unroll
  for (int mi = 0; mi < 6; ++mi)
#pragma unroll
    for (int ni = 0; ni < 4; ++ni) acc[mi][ni] = zero;

#define PH_MFMA(mh, nh) { __builtin_amdgcn_s_setprio(1); \
    _Pragma("unroll") for (int mi2 = 0; mi2 < 3; ++mi2) \
    _Pragma("unroll") for (int ni2 = 0; ni2 < 2; ++ni2) \
    _Pragma("unroll") for (int ks = 0; ks < 2; ++ks) \
      acc[(mh) * 3 + mi2][(nh) * 2 + ni2] = \
        MFMA16(aF[mi2][ks], bF[(nh) * 2 + ni2][ks], acc[(mh) * 3 + mi2][(nh) * 2 + ni2]); \
    __builtin_amdgcn_s_setprio(0); }

  // ---- prologue: stage tile 0 (7 loads)
  STAGE_B(0, 0, 0); STAGE_B(0, 1, 0); STAGE_B(0, 2, 0); STAGE_B(0, 3, 0);
  STAGE_A(0, 0, 0); STAGE_A(0, 2, 0); STAGE_A(0, 1, 0);
  asm volatile("s_waitcnt vmcnt(0)" ::: "memory");
  __builtin_amdgcn_s_barrier();

  int cur = 0;
  for (int t = 0; t < nt - 1; ++t) {
    const int k1 = (t + 1) * 64;
    // p0: quadrant (0,0)
    LDB(cur, 0); LDA(cur, 0);
    STAGE_B(cur ^ 1, 0, k1); STAGE_B(cur ^ 1, 1, k1);
    __builtin_amdgcn_s_barrier();
    PH_MFMA(0, 0);
    __builtin_amdgcn_s_barrier();
    // p1: quadrant (0,1)
    LDB(cur, 1);
    STAGE_A(cur ^ 1, 0, k1); STAGE_A(cur ^ 1, 2, k1);
    asm volatile("s_waitcnt vmcnt(4)" ::: "memory");   // drains this tile's A1
    __builtin_amdgcn_s_barrier();
    PH_MFMA(0, 1);
    __builtin_amdgcn_s_barrier();
    // p2: quadrant (1,0)
    LDA(cur, 1);
    STAGE_B(cur ^ 1, 2, k1); STAGE_B(cur ^ 1, 3, k1);
    __builtin_amdgcn_s_barrier();
    PH_MFMA(1, 0);
    __builtin_amdgcn_s_barrier();
    // p3: quadrant (1,1)
    STAGE_A(cur ^ 1, 1, k1);
    asm volatile("s_waitcnt vmcnt(1)" ::: "memory");   // next tile ready except its A1
    __builtin_amdgcn_s_barrier();
    PH_MFMA(1, 1);
    __builtin_amdgcn_s_barrier();
    cur ^= 1;
  }
  // ---- last tile (no staging)
  LDB(cur, 0); LDA(cur, 0);
  __builtin_amdgcn_s_barrier();
  PH_MFMA(0, 0);
  __builtin_amdgcn_s_barrier();
  LDB(cur, 1);
  asm volatile("s_waitcnt vmcnt(0)" ::: "memory");     // drain last tile's A1
  __builtin_amdgcn_s_barrier();
  PH_MFMA(0, 1);
  __builtin_amdgcn_s_barrier();
  LDA(cur, 1);
  PH_MFMA(1, 0);
  PH_MFMA(1, 1);

  // ---- epilogue (bf16 paths bounce via the dead LDS buffer, per-wave 2176 shorts)
  short* bw = (short*)(lds + (cur ^ 1) * 28672) + w * 2176;
  const bool isCt = (RT > 0) && (bn * 256 >= colsplit);   // block-uniform (colsplit%256==0)
  const int qb0 = wr ? 48 : 0;       // q-local base for mh=0
  const int qb1 = wr ? 0 : 48;       // q-local base for mh=1

  if (isCt) {
    const int RTl = (RT > 0 ? RT : 1);
#pragma unroll
    for (int ni = 0; ni < 4; ++ni) {
      const float bs = bias[bn * 256 + wc * 64 + ni * 16 + c];
      // bounce tile: rows dd=c (16), cols q-local (96, stride 104)
#pragma unroll
      for (int mh = 0; mh < 2; ++mh)
#pragma unroll
        for (int mi2 = 0; mi2 < 3; ++mi2) {
          u16x4 pk;
#pragma unroll
          for (int r = 0; r < 4; ++r) pk[r] = f2bf(acc[mh * 3 + mi2][ni][r] + bs);
          *reinterpret_cast<u16x4*>(&bw[c * 104 + (mh ? qb1 : qb0) + mi2 * 16 + g * 4]) = pk;
        }
#pragma unroll
      for (int it = 0; it < 3; ++it) {
        const int idx = it * 64 + lane;          // 0..191
        const int dd = idx / 12, q8 = idx - dd * 12;
        const int ql = q8 * 8;
        short8 vx = *reinterpret_cast<const short8*>(&bw[dd * 104 + ql]);
        const int colp = bn * 256 + wc * 64 + ni * 16 + dd - colsplit;
        const int hh = colp >> 6, dl = colp & 63;
        const int qg = bm * 192 + wr * 96 + ql;
        const int bb = qg / RTl, q0 = qg - bb * RTl;
        *reinterpret_cast<short8*>(Ct + ((size_t)(bb * 16 + hh) * 64 + dl) * RTl + q0) = vx;
      }
    }
  } else if (Cf) {
#pragma unroll
    for (int ni = 0; ni < 4; ++ni) {
      const int col = bn * 256 + wc * 64 + ni * 16 + c;
      const float bs = bias[col];
#pragma unroll
      for (int mh = 0; mh < 2; ++mh)
#pragma unroll
        for (int mi2 = 0; mi2 < 3; ++mi2) {
          const int row0 = bm * 192 + (mh ? rowb1 : rowb0) + mi2 * 16 + g * 4;
#pragma unroll
          for (int r = 0; r < 4; ++r)
            Cf[(size_t)(row0 + r) * ldc + col] = acc[mh * 3 + mi2][ni][r] + bs;
        }
    }
  } else {
    float bs4[4];
#pragma unroll
    for (int ni = 0; ni < 4; ++ni) bs4[ni] = bias[bn * 256 + wc * 64 + ni * 16 + c];
#pragma unroll
    for (int mh = 0; mh < 2; ++mh)
#pragma unroll
      for (int mi2 = 0; mi2 < 3; ++mi2) {
#pragma unroll
        for (int ni = 0; ni < 4; ++ni)
#pragma unroll
          for (int r = 0; r < 4; ++r)
            bw[(g * 4 + r) * 72 + ni * 16 + c] = (short)f2bf(acc[mh * 3 + mi2][ni][r] + bs4[ni]);
#pragma unroll
        for (int half = 0; half < 2; ++half) {
          const int rr = (lane >> 3) + half * 8;
          const int cc2 = (lane & 7) * 8;
          short8 vx = *reinterpret_cast<const short8*>(&bw[rr * 72 + cc2]);
          const int grow = bm * 192 + (mh ? rowb1 : rowb0) + mi2 * 16 + rr;
          *reinterpret_cast<short8*>(Cb + (size_t)grow * ldc + bn * 256 + wc * 64 + cc2) = vx;
        }
      }
  }
#undef AB
#undef BB
#undef STAGE_A
#undef STAGE_B
#undef LDA
#undef LDB
#undef PH_MFMA
}

// ---------------------------------------------------------------- swizzled per-wave P-tile offsets
__device__ __forceinline__ int pvt_off(int q, int kbyte) { return q * 256 + (kbyte ^ ((q & 7) << 4)); }

// ---------------------------------------------------------------- attention stage A: xv + P^T + colsum partials
__global__ __launch_bounds__(256) void attn_xv(
    const bfu* __restrict__ Q, const bfu* __restrict__ Kl,
    const bfu* __restrict__ LVt, const float* __restrict__ mask,
    bfu* __restrict__ xv, bfu* __restrict__ PT, float* __restrict__ colpart)
{
  __shared__ short Ks[128 * 64];      // 16 KB, swizzled
  __shared__ short LVs[64 * 128];     // 16 KB, swizzled within 128B half-rows
  __shared__ short PvT[4][2048];      // per-wave 16x128 P tile; reused as bounce buf

  const int blk = blockIdx.x;
  const int bh = blk & 511, qc = blk >> 9;
  const int b = bh >> 4, h = bh & 15;
  const int t = threadIdx.x, l = t & 63, w = t >> 6;
  const int g = l >> 4, c = l & 15;
  const int qt = qc * 4 + w;

  const bfu* Qp  = Q   + ((size_t)b * 576 * 1024 + h * 64);
  const bfu* Kp  = Kl  + ((size_t)b * 128 * 1024 + h * 64);
  const bfu* LVp = LVt + (size_t)bh * 64 * 128;
  const f32x4 zero = {0.f, 0.f, 0.f, 0.f};

  {
    const int kr = l >> 3;
    const bfu* sK = Kp + (size_t)(w * 8 + kr) * 1024 + (((l & 7) ^ kr) * 8);
#pragma unroll
    for (int i = 0; i < 4; ++i)
      gload_lds16(sK + (size_t)(i * 32) * 1024, (void*)&Ks[(i * 32 + w * 8) * 64]);
    const int lr = l >> 4;
    const int key = (w * 4 + lr) & 7;
    const bfu* sLV = LVp + (size_t)(w * 4 + lr) * 128 + ((l >> 3) & 1) * 64 + (((l & 7) ^ key) * 8);
#pragma unroll
    for (int i = 0; i < 4; ++i)
      gload_lds16(sLV + (size_t)(i * 16) * 128, (void*)&LVs[(i * 16 + w * 4) * 128]);
  }
  float mk[8];
#pragma unroll
  for (int kt = 0; kt < 8; ++kt) mk[kt] = mask[kt * 16 + c];
  __syncthreads();

  f32x4 sacc[8];
#pragma unroll
  for (int kt = 0; kt < 8; ++kt) sacc[kt] = zero;
  __builtin_amdgcn_s_setprio(1);
#pragma unroll
  for (int kk = 0; kk < 2; ++kk) {
    short8 aq = *reinterpret_cast<const short8*>(Qp + (size_t)(qt * 16 + c) * 1024 + kk * 32 + g * 8);
#pragma unroll
    for (int kt = 0; kt < 8; ++kt) {
      short8 bk = *reinterpret_cast<const short8*>(
          &Ks[(kt * 16 + c) * 64 + (((kk * 4 + g) ^ (c & 7)) * 8)]);
      sacc[kt] = MFMA16(aq, bk, sacc[kt]);
    }
  }
  __builtin_amdgcn_s_setprio(0);

  char* myPv = (char*)&PvT[w][0];
  float rs[4] = {0, 0, 0, 0};
  float colacc[8];
#pragma unroll
  for (int kt = 0; kt < 8; ++kt) {
    u16x4 pk;
    float ca = 0.f;
#pragma unroll
    for (int r = 0; r < 4; ++r) {
      float Ev = __expf(fmaf(sacc[kt][r], SCALE_QK, mk[kt]));
      rs[r] += Ev;
      ca += Ev;
      pk[r] = f2bf(Ev);
      *reinterpret_cast<unsigned short*>(myPv + pvt_off(g * 4 + r, 2 * (kt * 16 + c))) = pk[r];
    }
    colacc[kt] = ca;
    *reinterpret_cast<u16x4*>(PT + ((size_t)bh * 128 + kt * 16 + c) * 576 + qt * 16 + g * 4) = pk;
  }
#pragma unroll
  for (int r = 0; r < 4; ++r) {
    rs[r] += __shfl_xor(rs[r], 1);
    rs[r] += __shfl_xor(rs[r], 2);
    rs[r] += __shfl_xor(rs[r], 4);
    rs[r] += __shfl_xor(rs[r], 8);
  }

  short8 av[4];
#pragma unroll
  for (int kc = 0; kc < 4; ++kc)
    av[kc] = *reinterpret_cast<const short8*>(myPv + pvt_off(c, kc * 64 + g * 16));
  f32x4 oxv[4];
#pragma unroll
  for (int dt = 0; dt < 4; ++dt) oxv[dt] = zero;
  __builtin_amdgcn_s_setprio(1);
#pragma unroll
  for (int dt = 0; dt < 4; ++dt)
#pragma unroll
    for (int kc = 0; kc < 4; ++kc) {
      short8 bv = *reinterpret_cast<const short8*>(
          &LVs[(dt * 16 + c) * 128 + (kc >> 1) * 64 + ((((kc & 1) * 4 + g) ^ (c & 7)) * 8)]);
      oxv[dt] = MFMA16(av[kc], bv, oxv[dt]);
    }
  __builtin_amdgcn_s_setprio(0);
#pragma unroll
  for (int r = 0; r < 4; ++r) rs[r] = 1.0f / rs[r];

  short* bw = (short*)&PvT[w][0];
#pragma unroll
  for (int dt = 0; dt < 4; ++dt)
#pragma unroll
    for (int r = 0; r < 4; ++r)
      bw[(g * 4 + r) * 72 + dt * 16 + c] = (short)f2bf(oxv[dt][r] * rs[r]);
#pragma unroll
  for (int half = 0; half < 2; ++half) {
    const int rr = (l >> 3) + half * 8;
    const int cc = (l & 7) * 8;
    short8 vx = *reinterpret_cast<const short8*>(&bw[rr * 72 + cc]);
    *reinterpret_cast<short8*>(xv + (size_t)(b * 576 + qt * 16 + rr) * 1024 + h * 64 + cc) = vx;
  }

#pragma unroll
  for (int kt = 0; kt < 8; ++kt) {
    colacc[kt] += __shfl_xor(colacc[kt], 16);
    colacc[kt] += __shfl_xor(colacc[kt], 32);
  }
  if (g == 0) {
#pragma unroll
    for (int kt = 0; kt < 8; ++kt)
      colpart[(size_t)(bh * 36 + qt) * 128 + kt * 16 + c] = colacc[kt];
  }
}

// ---------------------------------------------------------------- attention stage B: xl = P^T @ VV / colsum
__global__ __launch_bounds__(64) void attn_xl(
    const bfu* __restrict__ PT, const bfu* __restrict__ VVt,
    const float* __restrict__ colpart, bfu* __restrict__ xl)
{
  __shared__ short XL[1168];

  const int blk = blockIdx.x;
  const int bh = blk & 511, kt = blk >> 9;
  const int b = bh >> 4, h = bh & 15;
  const int l = threadIdx.x;
  const int g = l >> 4, c = l & 15;

  const bfu* PTb  = PT  + ((size_t)bh * 128 + kt * 16 + c) * 576;
  const bfu* VVp  = VVt + (size_t)bh * 64 * 576;
  const f32x4 zero = {0.f, 0.f, 0.f, 0.f};

  float s = 0.f;
  const float* cp = colpart + (size_t)bh * 36 * 128 + kt * 16 + c;
#pragma unroll
  for (int qc = 0; qc < 36; ++qc) s += cp[qc * 128];
  float sinv = 1.0f / s;
  float ci[4];
#pragma unroll
  for (int r = 0; r < 4; ++r) ci[r] = __shfl(sinv, g * 4 + r);

  f32x4 acc[4];
#pragma unroll
  for (int dt = 0; dt < 4; ++dt) acc[dt] = zero;

  __builtin_amdgcn_s_setprio(1);
  for (int p = 0; p < 18; ++p) {
    short8 ap = *reinterpret_cast<const short8*>(PTb + p * 32 + g * 8);
#pragma unroll
    for (int dt = 0; dt < 4; ++dt) {
      short8 bv = *reinterpret_cast<const short8*>(VVp + (size_t)(dt * 16 + c) * 576 + p * 32 + g * 8);
      acc[dt] = MFMA16(ap, bv, acc[dt]);
    }
  }
  __builtin_amdgcn_s_setprio(0);

#pragma unroll
  for (int dt = 0; dt < 4; ++dt)
#pragma unroll
    for (int r = 0; r < 4; ++r)
      XL[(g * 4 + r) * 72 + dt * 16 + c] = (short)f2bf(acc[dt][r] * ci[r]);
#pragma unroll
  for (int half = 0; half < 2; ++half) {
    const int rr = (l >> 3) + half * 8;
    const int cc = (l & 7) * 8;
    short8 vx = *reinterpret_cast<const short8*>(&XL[rr * 72 + cc]);
    *reinterpret_cast<short8*>(xl + (size_t)(b * 128 + kt * 16 + rr) * 1024 + h * 64 + cc) = vx;
  }
}

// ---------------------------------------------------------------- host
static inline int cvt_grid(int n4) {
  int g = (n4 + 255) / 256;
  return g > 4096 ? 4096 : g;
}

extern "C" void kernel_launch(void* const* d_in, const int* in_sizes, int n_in,
                              void* d_out, int out_size, void* d_ws, size_t ws_size,
                              hipStream_t stream)
{
  const float* v    = (const float*)d_in[0];
  const float* lx   = (const float*)d_in[1];
  const float* mask = (const float*)d_in[2];
  const float* Wvq  = (const float*)d_in[3];
  const float* bvq  = (const float*)d_in[4];
  const float* Wlk  = (const float*)d_in[5];
  const float* blk  = (const float*)d_in[6];
  const float* Wvv  = (const float*)d_in[7];
  const float* bvv  = (const float*)d_in[8];
  const float* Wlv  = (const float*)d_in[9];
  const float* blv  = (const float*)d_in[10];
  const float* Wvo  = (const float*)d_in[11];
  const float* bvo  = (const float*)d_in[12];
  const float* Wlo  = (const float*)d_in[13];
  const float* blo  = (const float*)d_in[14];

  float* out_xv = (float*)d_out;                       // 18432 x 1024
  float* out_xl = out_xv + (size_t)18432 * 1024;       // 4096 x 768

  bfu* ws   = (bfu*)d_ws;
  bfu* vb   = ws;                      // 18874368 (later aliased as xv bf16)
  bfu* lb   = vb   + 18874368;         // 3145728  (later aliased by colpart)
  bfu* wqv  = lb   + 3145728;          // 2097152  [Wvq ; Wvv] (2048x1024)
  bfu* wklv = wqv  + 2097152;          // 1572864  [Wlk ; Wlv] (2048x768)
  bfu* wvo  = wklv + 1572864;          // 1048576
  bfu* wlo  = wvo  + 1048576;          // 786432
  bfu* Qb   = wlo  + 786432;           // 18874368  [18432][1024] bf16
  bfu* VVt  = Qb   + 18874368;         // 18874368  [bh][64][576]
  bfu* Kb   = VVt  + 18874368;         // 4194304   [4096][1024] (later aliased as xl bf16)
  bfu* LVt  = Kb   + 4194304;          // 4194304   [bh][64][128]
  bfu* PT   = LVt  + 4194304;          // 37748736  [bh][128][576]
  float* biasqv = (float*)(PT + 37748736);   // 2048 f32  [bvq ; bvv]
  float* biaskl = biasqv + 2048;             // 2048 f32  [blk ; blv]
  float* colpart = (float*)lb;               // 512*36*128 f32, aliases lb/wqv (dead by then)

  // 1) converts + bias concat
  cvt_f32_bf16<<<cvt_grid(18874368 / 4), 256, 0, stream>>>(v, vb, 18874368 / 4);
  CvtArgs ca;
  ca.src[0] = lx;  ca.dst[0] = lb;             ca.n4[0] = 3145728 / 4;
  ca.src[1] = Wvq; ca.dst[1] = wqv;            ca.n4[1] = 1048576 / 4;
  ca.src[2] = Wvv; ca.dst[2] = wqv + 1048576;  ca.n4[2] = 1048576 / 4;
  ca.src[3] = Wlk; ca.dst[3] = wklv;           ca.n4[3] = 786432 / 4;
  ca.src[4] = Wlv; ca.dst[4] = wklv + 786432;  ca.n4[4] = 786432 / 4;
  ca.src[5] = Wvo; ca.dst[5] = wvo;            ca.n4[5] = 1048576 / 4;
  ca.src[6] = Wlo; ca.dst[6] = wlo;            ca.n4[6] = 786432 / 4;
  cvt_multi<<<dim3(1024, 7), 256, 0, stream>>>(ca);
  hipMemcpyAsync(biasqv,        bvq, 1024 * sizeof(float), hipMemcpyDeviceToDevice, stream);
  hipMemcpyAsync(biasqv + 1024, bvv, 1024 * sizeof(float), hipMemcpyDeviceToDevice, stream);
  hipMemcpyAsync(biaskl,        blk, 1024 * sizeof(float), hipMemcpyDeviceToDevice, stream);
  hipMemcpyAsync(biaskl + 1024, blv, 1024 * sizeof(float), hipMemcpyDeviceToDevice, stream);

  // 2) projections: QV on 192x256 8-phase kernel (768 blocks = 3 exact rounds);
  //    KL on the 128-tile kernel
  gemm192<576><<<96 * 8, 512, 0, stream>>>(vb, wqv, biasqv, Qb, nullptr, VVt, 1024, 1024,
                                           18432, 2048, 1024, 8);
  gemm_bt<<<32 * 16, 256, 0, stream>>>(lb, wklv, biaskl, Kb, nullptr, LVt, 128, 1024, 1024,
                                       4096, 2048, 768, 16);

  // 3) attention: 4-wave blocks with K/LV in LDS (xv -> vb alias, xl -> Kb alias)
  attn_xv<<<512 * 9, 256, 0, stream>>>(Qb, Kb, LVt, mask, vb, PT, colpart);
  attn_xl<<<512 * 8, 64, 0, stream>>>(PT, VVt, colpart, Kb);

  // 4) output GEMMs: out_xv on 192x256 kernel (384 blocks = 1.5 rounds), out_xl on 128-tile
  gemm192<0><<<96 * 4, 512, 0, stream>>>(vb, wvo, bvo, nullptr, out_xv, nullptr, 1 << 30, 1024,
                                         18432, 1024, 1024, 4);
  gemm_bt<<<32 * 6, 256, 0, stream>>>(Kb, wlo, blo, nullptr, out_xl, nullptr, 0, 768, 768,
                                      4096, 768, 1024, 6);
}

// Round 12
// 313.471 us; speedup vs baseline: 1.1044x; 1.0458x over previous
//
#include <hip/hip_runtime.h>
#include <stdint.h>

// BiMultiHeadAttention (GLIP bi-attention), MI355X bf16 MFMA pipeline.
// B=32 VN=576 LN=128 E=1024 H=16 D=64, V_DIM=1024 L_DIM=768, SCALE=0.25.

typedef unsigned short bfu;   // bf16 storage
typedef __attribute__((ext_vector_type(4))) float f32x4;
typedef __attribute__((ext_vector_type(8))) short short8;
typedef __attribute__((ext_vector_type(4))) unsigned short u16x4;

#define MFMA16(a,b,c) __builtin_amdgcn_mfma_f32_16x16x32_bf16((a),(b),(c),0,0,0)
#define SCALE_QK 0.25f

__device__ __forceinline__ unsigned short f2bf(float x) {
  unsigned int u = __float_as_uint(x);
  u += 0x7fffu + ((u >> 16) & 1u);   // round-to-nearest-even
  return (unsigned short)(u >> 16);
}

__device__ __forceinline__ void gload_lds16(const void* g, void* l) {
  __builtin_amdgcn_global_load_lds(
      reinterpret_cast<__attribute__((address_space(1))) void*>(
          reinterpret_cast<uintptr_t>(g)),
      reinterpret_cast<__attribute__((address_space(3))) void*>(
          (uint32_t)reinterpret_cast<uintptr_t>(l)),
      16, 0, 0);
}

// ---------------------------------------------------------------- converts
__global__ void cvt_f32_bf16(const float* __restrict__ x, bfu* __restrict__ y, int n4) {
  for (int i = blockIdx.x * blockDim.x + threadIdx.x; i < n4; i += gridDim.x * blockDim.x) {
    const float4 f = *reinterpret_cast<const float4*>(x + (size_t)i * 4);
    u16x4 o;
    o[0] = f2bf(f.x); o[1] = f2bf(f.y); o[2] = f2bf(f.z); o[3] = f2bf(f.w);
    *reinterpret_cast<u16x4*>(y + (size_t)i * 4) = o;
  }
}

struct CvtArgs {
  const float* src[7];
  bfu* dst[7];
  int n4[7];
};

__global__ void cvt_multi(CvtArgs a) {
  const int s = blockIdx.y;
  const float* __restrict__ x = a.src[s];
  bfu* __restrict__ y = a.dst[s];
  const int n4 = a.n4[s];
  for (int i = blockIdx.x * blockDim.x + threadIdx.x; i < n4; i += gridDim.x * blockDim.x) {
    const float4 f = *reinterpret_cast<const float4*>(x + (size_t)i * 4);
    u16x4 o;
    o[0] = f2bf(f.x); o[1] = f2bf(f.y); o[2] = f2bf(f.z); o[3] = f2bf(f.w);
    *reinterpret_cast<u16x4*>(y + (size_t)i * 4) = o;
  }
}

// ---------------------------------------------------------------- GEMM 128-tile (m97 structure) — R5 version
__global__ __launch_bounds__(256) void gemm_bt(
    const bfu* __restrict__ A, const bfu* __restrict__ W, const float* __restrict__ bias,
    bfu* __restrict__ Cb, float* __restrict__ Cf, bfu* __restrict__ Ct, int R, int colsplit,
    int ldc, int M, int N, int K, int nbn)
{
  __shared__ bfu As[128 * 32];
  __shared__ bfu Bs[128 * 32];
  const int nbm = M >> 7;
  const int bid = blockIdx.x;
  int bm, bn;
  if ((nbm & 7) == 0) {             // bijective XCD-aware swizzle
    const int xcd = bid & 7, j = bid >> 3;
    const int jm = j / nbn;
    bm = xcd * (nbm >> 3) + jm;
    bn = j - jm * nbn;
  } else { bm = bid / nbn; bn = bid - (bid / nbn) * nbn; }

  const int t = threadIdx.x, l = t & 63, w = t >> 6;
  const int g = l >> 4, c = l & 15;
  const int wr = (w >> 1) * 64, wc = (w & 1) * 64;

  f32x4 zero = {0.f, 0.f, 0.f, 0.f};
  f32x4 acc[4][4];
  for (int m = 0; m < 4; ++m)
    for (int n = 0; n < 4; ++n) acc[m][n] = zero;

  const int rowA = l >> 2;
  const int kb   = (l & 3) * 16;

  for (int k0 = 0; k0 < K; k0 += 32) {
#pragma unroll
    for (int i = 0; i < 2; ++i) {
      int chunk = w * 2 + i;
      int r = chunk * 16 + rowA;
      const char* ga = (const char*)(A + (size_t)(bm * 128 + r) * K + k0) + kb;
      const char* gb = (const char*)(W + (size_t)(bn * 128 + r) * K + k0) + kb;
      gload_lds16(ga, (char*)As + chunk * 1024);
      gload_lds16(gb, (char*)Bs + chunk * 1024);
    }
    __syncthreads();
    short8 a[4], bf[4];
#pragma unroll
    for (int m = 0; m < 4; ++m)
      a[m] = *reinterpret_cast<const short8*>(&As[(wr + m * 16 + c) * 32 + g * 8]);
#pragma unroll
    for (int n = 0; n < 4; ++n)
      bf[n] = *reinterpret_cast<const short8*>(&Bs[(wc + n * 16 + c) * 32 + g * 8]);
#pragma unroll
    for (int m = 0; m < 4; ++m)
#pragma unroll
      for (int n = 0; n < 4; ++n)
        acc[m][n] = MFMA16(a[m], bf[n], acc[m][n]);
    __syncthreads();
  }

#pragma unroll
  for (int n = 0; n < 4; ++n) {
    const int col = bn * 128 + wc + n * 16 + c;
    const float bs = bias[col];
    if (col >= colsplit) {
      const int colp = col - colsplit;
      const int hh = colp >> 6, dd = colp & 63;
#pragma unroll
      for (int m = 0; m < 4; ++m) {
        const int row0 = bm * 128 + wr + m * 16 + g * 4;
        const int bb = row0 / R, q0 = row0 - bb * R;
        u16x4 pk;
#pragma unroll
        for (int r = 0; r < 4; ++r) pk[r] = f2bf(acc[m][n][r] + bs);
        *reinterpret_cast<u16x4*>(Ct + ((size_t)(bb * 16 + hh) * 64 + dd) * R + q0) = pk;
      }
    } else {
#pragma unroll
      for (int m = 0; m < 4; ++m) {
        const int row0 = bm * 128 + wr + m * 16 + g * 4;
#pragma unroll
        for (int r = 0; r < 4; ++r) {
          float val = acc[m][n][r] + bs;
          size_t idx = (size_t)(row0 + r) * ldc + col;
          if (Cf) Cf[idx] = val;
          else    Cb[idx] = f2bf(val);
        }
      }
    }
  }
}

// ---------------------------------------------------------------- GEMM 288x256-tile, 8-phase schedule
// BM=288, BN=256, BK=64, 512 thr (8 waves: wr=w>>2, wc=w&3; wave half = 144 rows = 9 m-tiles
// split 5+4 into quadrants). Grid: QV = 64x8 = 512 blocks (2 exact rounds); out_xv = 64x4 = 256
// blocks (1 exact round, 1 block/CU).
// LDS 144 KiB: 2 bufs x (A 320x64 [rows 288-319 pad] + B 256x64); 128B-row XOR swizzle.
// m-quadrants: wr0: mh0 rows 0-79 (chunks A0,A1), mh1 rows 80-143 (A1,A2);
//              wr1: mh0 rows 208-287 (A3,A4), mh1 rows 144-207 (A2,A3).
// Staging per tile (9 loads): B0..B3@p0; A0,A1,A3,A4@p1; A2@p2. Waits: vmcnt(8)@p1 (drains
// prev A2, 3-phase lead), vmcnt(1)@p3 (drains all but this tile's A2, >=2-phase lead) -- never 0.
template<int RT>
__global__ __launch_bounds__(512, 2) void gemm288(
    const bfu* __restrict__ A, const bfu* __restrict__ W, const float* __restrict__ bias,
    bfu* __restrict__ Cb, float* __restrict__ Cf, bfu* __restrict__ Ct, int colsplit,
    int ldc, int M, int N, int K, int nbn)
{
  __shared__ bfu lds[2 * 36864];      // 147456 B: per buf, A 20480 elems + B 16384 elems

  const int tid = threadIdx.x;
  const int w = tid >> 6, lane = tid & 63;
  const int g = lane >> 4, c = lane & 15;
  const int wr = w >> 2, wc = w & 3;
  const int rb0 = wr ? 208 : 0;       // mh0 row base (5 tiles)
  const int rb1 = wr ? 144 : 80;      // mh1 row base (4 tiles)

  const int nbm = M / 288;
  int bm, bn;
  { const int xcd = blockIdx.x & 7, j = blockIdx.x >> 3;
    const int jm = j / nbn; bm = xcd * (nbm >> 3) + jm; bn = j - jm * nbn; }

  const int nt = K >> 6;

  const int srow8 = lane >> 3;                     // 0..7
  const int sslot = lane & 7;
  const int swzE  = ((sslot * 16) ^ (srow8 << 4)) >> 1;   // pre-swizzled elem offset
  const bfu* srcA = A + (size_t)(bm * 288 + 8 * w + srow8) * K + swzE;
  const bfu* srcB = W + (size_t)(bn * 256 + 8 * w + srow8) * K + swzE;

#define AB(cur) (lds + (cur) * 36864)
#define BB(cur) (lds + (cur) * 36864 + 20480)
#define STAGE_A(cur, j, k0) gload_lds16(srcA + (size_t)(64 * (j)) * K + (k0), \
    (void*)(AB(cur) + (64 * (j) + 8 * w) * 64))
#define STAGE_B(cur, j, k0) gload_lds16(srcB + (size_t)(64 * (j)) * K + (k0), \
    (void*)(BB(cur) + (64 * (j) + 8 * w) * 64))

  short8 aF[5][2], bF[4][2];
  const int swzR = ((c & 7) << 3);                 // read-side swizzle (elems)

#define LDA(cur, mh, CNT) { _Pragma("unroll") for (int mi2 = 0; mi2 < (CNT); ++mi2) \
    _Pragma("unroll") for (int ks = 0; ks < 2; ++ks) \
      aF[mi2][ks] = *reinterpret_cast<const short8*>( \
        AB(cur) + (((mh) ? rb1 : rb0) + mi2 * 16 + c) * 64 + ((ks * 32 + g * 8) ^ swzR)); }
#define LDB(cur, nh) { _Pragma("unroll") for (int ni2 = 0; ni2 < 2; ++ni2) \
    _Pragma("unroll") for (int ks = 0; ks < 2; ++ks) \
      bF[(nh) * 2 + ni2][ks] = *reinterpret_cast<const short8*>( \
        BB(cur) + (wc * 64 + (nh) * 32 + ni2 * 16 + c) * 64 + ((ks * 32 + g * 8) ^ swzR)); }

  f32x4 acc[9][4];
  const f32x4 zero = {0.f, 0.f, 0.f, 0.f};
#pragma unroll
  for (int mi = 0; mi < 9; ++mi)
#pragma unroll
    for (int ni = 0; ni < 4; ++ni) acc[mi][ni] = zero;

#define PH_MFMA(mh, nh, CNT) { __builtin_amdgcn_s_setprio(1); \
    _Pragma("unroll") for (int mi2 = 0; mi2 < (CNT); ++mi2) \
    _Pragma("unroll") for (int ni2 = 0; ni2 < 2; ++ni2) \
    _Pragma("unroll") for (int ks = 0; ks < 2; ++ks) \
      acc[(mh) * 5 + mi2][(nh) * 2 + ni2] = \
        MFMA16(aF[mi2][ks], bF[(nh) * 2 + ni2][ks], acc[(mh) * 5 + mi2][(nh) * 2 + ni2]); \
    __builtin_amdgcn_s_setprio(0); }

  // ---- prologue: stage tile 0 fully (9 loads)
  STAGE_B(0, 0, 0); STAGE_B(0, 1, 0); STAGE_B(0, 2, 0); STAGE_B(0, 3, 0);
  STAGE_A(0, 0, 0); STAGE_A(0, 1, 0); STAGE_A(0, 3, 0); STAGE_A(0, 4, 0); STAGE_A(0, 2, 0);
  asm volatile("s_waitcnt vmcnt(0)" ::: "memory");
  __builtin_amdgcn_s_barrier();

  int cur = 0;
  for (int t = 0; t < nt - 1; ++t) {
    const int k1 = (t + 1) * 64;
    // p0: quadrant (0,0); stage all B of next tile
    LDB(cur, 0); LDA(cur, 0, 5);
    STAGE_B(cur ^ 1, 0, k1); STAGE_B(cur ^ 1, 1, k1);
    STAGE_B(cur ^ 1, 2, k1); STAGE_B(cur ^ 1, 3, k1);
    __builtin_amdgcn_s_barrier();
    PH_MFMA(0, 0, 5);
    __builtin_amdgcn_s_barrier();
    // p1: quadrant (0,1); stage A0,A1,A3,A4; wait drains prev tile's A2 (3-phase lead)
    LDB(cur, 1);
    STAGE_A(cur ^ 1, 0, k1); STAGE_A(cur ^ 1, 1, k1);
    STAGE_A(cur ^ 1, 3, k1); STAGE_A(cur ^ 1, 4, k1);
    asm volatile("s_waitcnt vmcnt(8)" ::: "memory");
    __builtin_amdgcn_s_barrier();
    PH_MFMA(0, 1, 5);
    __builtin_amdgcn_s_barrier();
    // p2: quadrant (1,0); stage A2
    LDA(cur, 1, 4);
    STAGE_A(cur ^ 1, 2, k1);
    __builtin_amdgcn_s_barrier();
    PH_MFMA(1, 0, 4);
    __builtin_amdgcn_s_barrier();
    // p3: quadrant (1,1); next tile ready except its A2 (all >=2-phase lead)
    asm volatile("s_waitcnt vmcnt(1)" ::: "memory");
    __builtin_amdgcn_s_barrier();
    PH_MFMA(1, 1, 4);
    __builtin_amdgcn_s_barrier();
    cur ^= 1;
  }
  // ---- last tile (no staging); vmcnt(0) drains prev tile's A2
  LDB(cur, 0); LDA(cur, 0, 5);
  __builtin_amdgcn_s_barrier();
  PH_MFMA(0, 0, 5);
  __builtin_amdgcn_s_barrier();
  LDB(cur, 1);
  asm volatile("s_waitcnt vmcnt(0)" ::: "memory");
  __builtin_amdgcn_s_barrier();
  PH_MFMA(0, 1, 5);
  __builtin_amdgcn_s_barrier();
  LDA(cur, 1, 4);
  PH_MFMA(1, 0, 4);
  PH_MFMA(1, 1, 4);

  // ---- epilogue (nt even => last tile used buf1; buf0 is dead, use as bounce)
  const bool isCt = (RT > 0) && (bn * 256 >= colsplit);   // block-uniform (colsplit%256==0)

  if (isCt) {
    const int RTl = (RT > 0 ? RT : 1);
    short* bw = (short*)lds + w * 2432;   // 16 x 152 per-wave tile
#pragma unroll
    for (int ni = 0; ni < 4; ++ni) {
      const float bs = bias[bn * 256 + wc * 64 + ni * 16 + c];
#pragma unroll
      for (int mh = 0; mh < 2; ++mh)
#pragma unroll
        for (int mi2 = 0; mi2 < 5; ++mi2) {
          if (mh == 1 && mi2 == 4) continue;
          const int qlb = wr ? (mh ? 0 : 64) : (mh ? 80 : 0);
          u16x4 pk;
#pragma unroll
          for (int r = 0; r < 4; ++r) pk[r] = f2bf(acc[mh * 5 + mi2][ni][r] + bs);
          *reinterpret_cast<u16x4*>(&bw[c * 152 + qlb + mi2 * 16 + g * 4]) = pk;
        }
#pragma unroll
      for (int it = 0; it < 5; ++it) {
        const int idx = it * 64 + lane;          // 0..287 (16 dd x 18 q8)
        if (idx < 288) {
          const int dd = idx / 18, q8 = idx - dd * 18;
          short8 vx = *reinterpret_cast<const short8*>(&bw[dd * 152 + q8 * 8]);
          const int colp = bn * 256 + wc * 64 + ni * 16 + dd - colsplit;
          const int hh = colp >> 6, dl = colp & 63;
          const int qg = bm * 288 + wr * 144 + q8 * 8;
          const int bb = qg / RTl, q0 = qg - bb * RTl;
          *reinterpret_cast<short8*>(Ct + ((size_t)(bb * 16 + hh) * 64 + dl) * RTl + q0) = vx;
        }
      }
    }
  } else if (Cf) {
#pragma unroll
    for (int ni = 0; ni < 4; ++ni) {
      const int col = bn * 256 + wc * 64 + ni * 16 + c;
      const float bs = bias[col];
#pragma unroll
      for (int mh = 0; mh < 2; ++mh)
#pragma unroll
        for (int mi2 = 0; mi2 < 5; ++mi2) {
          if (mh == 1 && mi2 == 4) continue;
          const int row0 = bm * 288 + (mh ? rb1 : rb0) + mi2 * 16 + g * 4;
#pragma unroll
          for (int r = 0; r < 4; ++r)
            Cf[(size_t)(row0 + r) * ldc + col] = acc[mh * 5 + mi2][ni][r] + bs;
        }
    }
  } else {
    short* bw = (short*)lds + w * 1216;   // 16 x 72 per-wave tile
    float bs4[4];
#pragma unroll
    for (int ni = 0; ni < 4; ++ni) bs4[ni] = bias[bn * 256 + wc * 64 + ni * 16 + c];
#pragma unroll
    for (int mh = 0; mh < 2; ++mh)
#pragma unroll
      for (int mi2 = 0; mi2 < 5; ++mi2) {
        if (mh == 1 && mi2 == 4) continue;
#pragma unroll
        for (int ni = 0; ni < 4; ++ni)
#pragma unroll
          for (int r = 0; r < 4; ++r)
            bw[(g * 4 + r) * 72 + ni * 16 + c] = (short)f2bf(acc[mh * 5 + mi2][ni][r] + bs4[ni]);
#pragma unroll
        for (int half = 0; half < 2; ++half) {
          const int rr = (lane >> 3) + half * 8;
          const int cc2 = (lane & 7) * 8;
          short8 vx = *reinterpret_cast<const short8*>(&bw[rr * 72 + cc2]);
          const int grow = bm * 288 + (mh ? rb1 : rb0) + mi2 * 16 + rr;
          *reinterpret_cast<short8*>(Cb + (size_t)grow * ldc + bn * 256 + wc * 64 + cc2) = vx;
        }
      }
  }
#undef AB
#undef BB
#undef STAGE_A
#undef STAGE_B
#undef LDA
#undef LDB
#undef PH_MFMA
}

// ---------------------------------------------------------------- swizzled per-wave P-tile offsets
__device__ __forceinline__ int pvt_off(int q, int kbyte) { return q * 256 + (kbyte ^ ((q & 7) << 4)); }

// ---------------------------------------------------------------- attention stage A: xv + P^T + colsum partials
__global__ __launch_bounds__(256) void attn_xv(
    const bfu* __restrict__ Q, const bfu* __restrict__ Kl,
    const bfu* __restrict__ LVt, const float* __restrict__ mask,
    bfu* __restrict__ xv, bfu* __restrict__ PT, float* __restrict__ colpart)
{
  __shared__ short Ks[128 * 64];      // 16 KB, swizzled
  __shared__ short LVs[64 * 128];     // 16 KB, swizzled within 128B half-rows
  __shared__ short PvT[4][2048];      // per-wave 16x128 P tile; reused as bounce buf

  const int blk = blockIdx.x;
  const int bh = blk & 511, qc = blk >> 9;
  const int b = bh >> 4, h = bh & 15;
  const int t = threadIdx.x, l = t & 63, w = t >> 6;
  const int g = l >> 4, c = l & 15;
  const int qt = qc * 4 + w;

  const bfu* Qp  = Q   + ((size_t)b * 576 * 1024 + h * 64);
  const bfu* Kp  = Kl  + ((size_t)b * 128 * 1024 + h * 64);
  const bfu* LVp = LVt + (size_t)bh * 64 * 128;
  const f32x4 zero = {0.f, 0.f, 0.f, 0.f};

  {
    const int kr = l >> 3;
    const bfu* sK = Kp + (size_t)(w * 8 + kr) * 1024 + (((l & 7) ^ kr) * 8);
#pragma unroll
    for (int i = 0; i < 4; ++i)
      gload_lds16(sK + (size_t)(i * 32) * 1024, (void*)&Ks[(i * 32 + w * 8) * 64]);
    const int lr = l >> 4;
    const int key = (w * 4 + lr) & 7;
    const bfu* sLV = LVp + (size_t)(w * 4 + lr) * 128 + ((l >> 3) & 1) * 64 + (((l & 7) ^ key) * 8);
#pragma unroll
    for (int i = 0; i < 4; ++i)
      gload_lds16(sLV + (size_t)(i * 16) * 128, (void*)&LVs[(i * 16 + w * 4) * 128]);
  }
  float mk[8];
#pragma unroll
  for (int kt = 0; kt < 8; ++kt) mk[kt] = mask[kt * 16 + c];
  __syncthreads();

  f32x4 sacc[8];
#pragma unroll
  for (int kt = 0; kt < 8; ++kt) sacc[kt] = zero;
  __builtin_amdgcn_s_setprio(1);
#pragma unroll
  for (int kk = 0; kk < 2; ++kk) {
    short8 aq = *reinterpret_cast<const short8*>(Qp + (size_t)(qt * 16 + c) * 1024 + kk * 32 + g * 8);
#pragma unroll
    for (int kt = 0; kt < 8; ++kt) {
      short8 bk = *reinterpret_cast<const short8*>(
          &Ks[(kt * 16 + c) * 64 + (((kk * 4 + g) ^ (c & 7)) * 8)]);
      sacc[kt] = MFMA16(aq, bk, sacc[kt]);
    }
  }
  __builtin_amdgcn_s_setprio(0);

  char* myPv = (char*)&PvT[w][0];
  float rs[4] = {0, 0, 0, 0};
  float colacc[8];
#pragma unroll
  for (int kt = 0; kt < 8; ++kt) {
    u16x4 pk;
    float ca = 0.f;
#pragma unroll
    for (int r = 0; r < 4; ++r) {
      float Ev = __expf(fmaf(sacc[kt][r], SCALE_QK, mk[kt]));
      rs[r] += Ev;
      ca += Ev;
      pk[r] = f2bf(Ev);
      *reinterpret_cast<unsigned short*>(myPv + pvt_off(g * 4 + r, 2 * (kt * 16 + c))) = pk[r];
    }
    colacc[kt] = ca;
    *reinterpret_cast<u16x4*>(PT + ((size_t)bh * 128 + kt * 16 + c) * 576 + qt * 16 + g * 4) = pk;
  }
#pragma unroll
  for (int r = 0; r < 4; ++r) {
    rs[r] += __shfl_xor(rs[r], 1);
    rs[r] += __shfl_xor(rs[r], 2);
    rs[r] += __shfl_xor(rs[r], 4);
    rs[r] += __shfl_xor(rs[r], 8);
  }

  short8 av[4];
#pragma unroll
  for (int kc = 0; kc < 4; ++kc)
    av[kc] = *reinterpret_cast<const short8*>(myPv + pvt_off(c, kc * 64 + g * 16));
  f32x4 oxv[4];
#pragma unroll
  for (int dt = 0; dt < 4; ++dt) oxv[dt] = zero;
  __builtin_amdgcn_s_setprio(1);
#pragma unroll
  for (int dt = 0; dt < 4; ++dt)
#pragma unroll
    for (int kc = 0; kc < 4; ++kc) {
      short8 bv = *reinterpret_cast<const short8*>(
          &LVs[(dt * 16 + c) * 128 + (kc >> 1) * 64 + ((((kc & 1) * 4 + g) ^ (c & 7)) * 8)]);
      oxv[dt] = MFMA16(av[kc], bv, oxv[dt]);
    }
  __builtin_amdgcn_s_setprio(0);
#pragma unroll
  for (int r = 0; r < 4; ++r) rs[r] = 1.0f / rs[r];

  short* bw = (short*)&PvT[w][0];
#pragma unroll
  for (int dt = 0; dt < 4; ++dt)
#pragma unroll
    for (int r = 0; r < 4; ++r)
      bw[(g * 4 + r) * 72 + dt * 16 + c] = (short)f2bf(oxv[dt][r] * rs[r]);
#pragma unroll
  for (int half = 0; half < 2; ++half) {
    const int rr = (l >> 3) + half * 8;
    const int cc = (l & 7) * 8;
    short8 vx = *reinterpret_cast<const short8*>(&bw[rr * 72 + cc]);
    *reinterpret_cast<short8*>(xv + (size_t)(b * 576 + qt * 16 + rr) * 1024 + h * 64 + cc) = vx;
  }

#pragma unroll
  for (int kt = 0; kt < 8; ++kt) {
    colacc[kt] += __shfl_xor(colacc[kt], 16);
    colacc[kt] += __shfl_xor(colacc[kt], 32);
  }
  if (g == 0) {
#pragma unroll
    for (int kt = 0; kt < 8; ++kt)
      colpart[(size_t)(bh * 36 + qt) * 128 + kt * 16 + c] = colacc[kt];
  }
}

// ---------------------------------------------------------------- attention stage B: xl = P^T @ VV / colsum
__global__ __launch_bounds__(64) void attn_xl(
    const bfu* __restrict__ PT, const bfu* __restrict__ VVt,
    const float* __restrict__ colpart, bfu* __restrict__ xl)
{
  __shared__ short XL[1168];

  const int blk = blockIdx.x;
  const int bh = blk & 511, kt = blk >> 9;
  const int b = bh >> 4, h = bh & 15;
  const int l = threadIdx.x;
  const int g = l >> 4, c = l & 15;

  const bfu* PTb  = PT  + ((size_t)bh * 128 + kt * 16 + c) * 576;
  const bfu* VVp  = VVt + (size_t)bh * 64 * 576;
  const f32x4 zero = {0.f, 0.f, 0.f, 0.f};

  float s = 0.f;
  const float* cp = colpart + (size_t)bh * 36 * 128 + kt * 16 + c;
#pragma unroll
  for (int qc = 0; qc < 36; ++qc) s += cp[qc * 128];
  float sinv = 1.0f / s;
  float ci[4];
#pragma unroll
  for (int r = 0; r < 4; ++r) ci[r] = __shfl(sinv, g * 4 + r);

  f32x4 acc[4];
#pragma unroll
  for (int dt = 0; dt < 4; ++dt) acc[dt] = zero;

  __builtin_amdgcn_s_setprio(1);
  for (int p = 0; p < 18; ++p) {
    short8 ap = *reinterpret_cast<const short8*>(PTb + p * 32 + g * 8);
#pragma unroll
    for (int dt = 0; dt < 4; ++dt) {
      short8 bv = *reinterpret_cast<const short8*>(VVp + (size_t)(dt * 16 + c) * 576 + p * 32 + g * 8);
      acc[dt] = MFMA16(ap, bv, acc[dt]);
    }
  }
  __builtin_amdgcn_s_setprio(0);

#pragma unroll
  for (int dt = 0; dt < 4; ++dt)
#pragma unroll
    for (int r = 0; r < 4; ++r)
      XL[(g * 4 + r) * 72 + dt * 16 + c] = (short)f2bf(acc[dt][r] * ci[r]);
#pragma unroll
  for (int half = 0; half < 2; ++half) {
    const int rr = (l >> 3) + half * 8;
    const int cc = (l & 7) * 8;
    short8 vx = *reinterpret_cast<const short8*>(&XL[rr * 72 + cc]);
    *reinterpret_cast<short8*>(xl + (size_t)(b * 128 + kt * 16 + rr) * 1024 + h * 64 + cc) = vx;
  }
}

// ---------------------------------------------------------------- host
static inline int cvt_grid(int n4) {
  int g = (n4 + 255) / 256;
  return g > 4096 ? 4096 : g;
}

extern "C" void kernel_launch(void* const* d_in, const int* in_sizes, int n_in,
                              void* d_out, int out_size, void* d_ws, size_t ws_size,
                              hipStream_t stream)
{
  const float* v    = (const float*)d_in[0];
  const float* lx   = (const float*)d_in[1];
  const float* mask = (const float*)d_in[2];
  const float* Wvq  = (const float*)d_in[3];
  const float* bvq  = (const float*)d_in[4];
  const float* Wlk  = (const float*)d_in[5];
  const float* blk  = (const float*)d_in[6];
  const float* Wvv  = (const float*)d_in[7];
  const float* bvv  = (const float*)d_in[8];
  const float* Wlv  = (const float*)d_in[9];
  const float* blv  = (const float*)d_in[10];
  const float* Wvo  = (const float*)d_in[11];
  const float* bvo  = (const float*)d_in[12];
  const float* Wlo  = (const float*)d_in[13];
  const float* blo  = (const float*)d_in[14];

  float* out_xv = (float*)d_out;                       // 18432 x 1024
  float* out_xl = out_xv + (size_t)18432 * 1024;       // 4096 x 768

  bfu* ws   = (bfu*)d_ws;
  bfu* vb   = ws;                      // 18874368 (later aliased as xv bf16)
  bfu* lb   = vb   + 18874368;         // 3145728  (later aliased by colpart)
  bfu* wqv  = lb   + 3145728;          // 2097152  [Wvq ; Wvv] (2048x1024)
  bfu* wklv = wqv  + 2097152;          // 1572864  [Wlk ; Wlv] (2048x768)
  bfu* wvo  = wklv + 1572864;          // 1048576
  bfu* wlo  = wvo  + 1048576;          // 786432
  bfu* Qb   = wlo  + 786432;           // 18874368  [18432][1024] bf16
  bfu* VVt  = Qb   + 18874368;         // 18874368  [bh][64][576]
  bfu* Kb   = VVt  + 18874368;         // 4194304   [4096][1024] (later aliased as xl bf16)
  bfu* LVt  = Kb   + 4194304;          // 4194304   [bh][64][128]
  bfu* PT   = LVt  + 4194304;          // 37748736  [bh][128][576]
  float* biasqv = (float*)(PT + 37748736);   // 2048 f32  [bvq ; bvv]
  float* biaskl = biasqv + 2048;             // 2048 f32  [blk ; blv]
  float* colpart = (float*)lb;               // 512*36*128 f32, aliases lb/wqv (dead by then)

  // 1) converts + bias concat
  cvt_f32_bf16<<<cvt_grid(18874368 / 4), 256, 0, stream>>>(v, vb, 18874368 / 4);
  CvtArgs ca;
  ca.src[0] = lx;  ca.dst[0] = lb;             ca.n4[0] = 3145728 / 4;
  ca.src[1] = Wvq; ca.dst[1] = wqv;            ca.n4[1] = 1048576 / 4;
  ca.src[2] = Wvv; ca.dst[2] = wqv + 1048576;  ca.n4[2] = 1048576 / 4;
  ca.src[3] = Wlk; ca.dst[3] = wklv;           ca.n4[3] = 786432 / 4;
  ca.src[4] = Wlv; ca.dst[4] = wklv + 786432;  ca.n4[4] = 786432 / 4;
  ca.src[5] = Wvo; ca.dst[5] = wvo;            ca.n4[5] = 1048576 / 4;
  ca.src[6] = Wlo; ca.dst[6] = wlo;            ca.n4[6] = 786432 / 4;
  cvt_multi<<<dim3(1024, 7), 256, 0, stream>>>(ca);
  hipMemcpyAsync(biasqv,        bvq, 1024 * sizeof(float), hipMemcpyDeviceToDevice, stream);
  hipMemcpyAsync(biasqv + 1024, bvv, 1024 * sizeof(float), hipMemcpyDeviceToDevice, stream);
  hipMemcpyAsync(biaskl,        blk, 1024 * sizeof(float), hipMemcpyDeviceToDevice, stream);
  hipMemcpyAsync(biaskl + 1024, blv, 1024 * sizeof(float), hipMemcpyDeviceToDevice, stream);

  // 2) projections: QV on 288x256 kernel (512 blocks = 2 exact rounds); KL on 128-tile kernel
  gemm288<576><<<64 * 8, 512, 0, stream>>>(vb, wqv, biasqv, Qb, nullptr, VVt, 1024, 1024,
                                           18432, 2048, 1024, 8);
  gemm_bt<<<32 * 16, 256, 0, stream>>>(lb, wklv, biaskl, Kb, nullptr, LVt, 128, 1024, 1024,
                                       4096, 2048, 768, 16);

  // 3) attention: 4-wave blocks with K/LV in LDS (xv -> vb alias, xl -> Kb alias)
  attn_xv<<<512 * 9, 256, 0, stream>>>(Qb, Kb, LVt, mask, vb, PT, colpart);
  attn_xl<<<512 * 8, 64, 0, stream>>>(PT, VVt, colpart, Kb);

  // 4) output GEMMs: out_xv on 288x256 kernel (256 blocks = 1 exact round), out_xl on 128-tile
  gemm288<0><<<64 * 4, 512, 0, stream>>>(vb, wvo, bvo, nullptr, out_xv, nullptr, 1 << 30, 1024,
                                         18432, 1024, 1024, 4);
  gemm_bt<<<32 * 6, 256, 0, stream>>>(Kb, wlo, blo, nullptr, out_xl, nullptr, 0, 768, 768,
                                      4096, 768, 1024, 6);
}

// Round 13
// 256.530 us; speedup vs baseline: 1.3495x; 1.2220x over previous
//
#include <hip/hip_runtime.h>
#include <stdint.h>

// BiMultiHeadAttention (GLIP bi-attention), MI355X bf16 MFMA pipeline.
// B=32 VN=576 LN=128 E=1024 H=16 D=64, V_DIM=1024 L_DIM=768, SCALE=0.25.

typedef unsigned short bfu;   // bf16 storage
typedef __attribute__((ext_vector_type(4))) float f32x4;
typedef __attribute__((ext_vector_type(8))) short short8;
typedef __attribute__((ext_vector_type(4))) unsigned short u16x4;

#define MFMA16(a,b,c) __builtin_amdgcn_mfma_f32_16x16x32_bf16((a),(b),(c),0,0,0)
#define SCALE_QK 0.25f

__device__ __forceinline__ unsigned short f2bf(float x) {
  unsigned int u = __float_as_uint(x);
  u += 0x7fffu + ((u >> 16) & 1u);   // round-to-nearest-even
  return (unsigned short)(u >> 16);
}

__device__ __forceinline__ void gload_lds16(const void* g, void* l) {
  __builtin_amdgcn_global_load_lds(
      reinterpret_cast<__attribute__((address_space(1))) void*>(
          reinterpret_cast<uintptr_t>(g)),
      reinterpret_cast<__attribute__((address_space(3))) void*>(
          (uint32_t)reinterpret_cast<uintptr_t>(l)),
      16, 0, 0);
}

// ---------------------------------------------------------------- converts
__global__ void cvt_f32_bf16(const float* __restrict__ x, bfu* __restrict__ y, int n4) {
  for (int i = blockIdx.x * blockDim.x + threadIdx.x; i < n4; i += gridDim.x * blockDim.x) {
    const float4 f = *reinterpret_cast<const float4*>(x + (size_t)i * 4);
    u16x4 o;
    o[0] = f2bf(f.x); o[1] = f2bf(f.y); o[2] = f2bf(f.z); o[3] = f2bf(f.w);
    *reinterpret_cast<u16x4*>(y + (size_t)i * 4) = o;
  }
}

struct CvtArgs {
  const float* src[7];
  bfu* dst[7];
  int n4[7];
};

__global__ void cvt_multi(CvtArgs a) {
  const int s = blockIdx.y;
  const float* __restrict__ x = a.src[s];
  bfu* __restrict__ y = a.dst[s];
  const int n4 = a.n4[s];
  for (int i = blockIdx.x * blockDim.x + threadIdx.x; i < n4; i += gridDim.x * blockDim.x) {
    const float4 f = *reinterpret_cast<const float4*>(x + (size_t)i * 4);
    u16x4 o;
    o[0] = f2bf(f.x); o[1] = f2bf(f.y); o[2] = f2bf(f.z); o[3] = f2bf(f.w);
    *reinterpret_cast<u16x4*>(y + (size_t)i * 4) = o;
  }
}

// bias concat: one dispatch replaces 4 d2d memcpies
__global__ void bias_concat(const float* __restrict__ a, const float* __restrict__ b,
                            const float* __restrict__ c2, const float* __restrict__ d,
                            float* __restrict__ qv, float* __restrict__ kl) {
  const int i = threadIdx.x * 4;
  const float4* s;
  float* o;
  switch (blockIdx.x) {
    case 0: s = (const float4*)a;  o = qv;        break;
    case 1: s = (const float4*)b;  o = qv + 1024; break;
    case 2: s = (const float4*)c2; o = kl;        break;
    default: s = (const float4*)d; o = kl + 1024; break;
  }
  *reinterpret_cast<float4*>(o + i) = s[threadIdx.x];
}

// ---------------------------------------------------------------- GEMM 128-tile (m97 structure) — R5 version
__global__ __launch_bounds__(256) void gemm_bt(
    const bfu* __restrict__ A, const bfu* __restrict__ W, const float* __restrict__ bias,
    bfu* __restrict__ Cb, float* __restrict__ Cf, bfu* __restrict__ Ct, int R, int colsplit,
    int ldc, int M, int N, int K, int nbn)
{
  __shared__ bfu As[128 * 32];
  __shared__ bfu Bs[128 * 32];
  const int nbm = M >> 7;
  const int bid = blockIdx.x;
  int bm, bn;
  if ((nbm & 7) == 0) {             // bijective XCD-aware swizzle
    const int xcd = bid & 7, j = bid >> 3;
    const int jm = j / nbn;
    bm = xcd * (nbm >> 3) + jm;
    bn = j - jm * nbn;
  } else { bm = bid / nbn; bn = bid - (bid / nbn) * nbn; }

  const int t = threadIdx.x, l = t & 63, w = t >> 6;
  const int g = l >> 4, c = l & 15;
  const int wr = (w >> 1) * 64, wc = (w & 1) * 64;

  f32x4 zero = {0.f, 0.f, 0.f, 0.f};
  f32x4 acc[4][4];
  for (int m = 0; m < 4; ++m)
    for (int n = 0; n < 4; ++n) acc[m][n] = zero;

  const int rowA = l >> 2;
  const int kb   = (l & 3) * 16;

  for (int k0 = 0; k0 < K; k0 += 32) {
#pragma unroll
    for (int i = 0; i < 2; ++i) {
      int chunk = w * 2 + i;
      int r = chunk * 16 + rowA;
      const char* ga = (const char*)(A + (size_t)(bm * 128 + r) * K + k0) + kb;
      const char* gb = (const char*)(W + (size_t)(bn * 128 + r) * K + k0) + kb;
      gload_lds16(ga, (char*)As + chunk * 1024);
      gload_lds16(gb, (char*)Bs + chunk * 1024);
    }
    __syncthreads();
    short8 a[4], bf[4];
#pragma unroll
    for (int m = 0; m < 4; ++m)
      a[m] = *reinterpret_cast<const short8*>(&As[(wr + m * 16 + c) * 32 + g * 8]);
#pragma unroll
    for (int n = 0; n < 4; ++n)
      bf[n] = *reinterpret_cast<const short8*>(&Bs[(wc + n * 16 + c) * 32 + g * 8]);
#pragma unroll
    for (int m = 0; m < 4; ++m)
#pragma unroll
      for (int n = 0; n < 4; ++n)
        acc[m][n] = MFMA16(a[m], bf[n], acc[m][n]);
    __syncthreads();
  }

#pragma unroll
  for (int n = 0; n < 4; ++n) {
    const int col = bn * 128 + wc + n * 16 + c;
    const float bs = bias[col];
    if (col >= colsplit) {
      const int colp = col - colsplit;
      const int hh = colp >> 6, dd = colp & 63;
#pragma unroll
      for (int m = 0; m < 4; ++m) {
        const int row0 = bm * 128 + wr + m * 16 + g * 4;
        const int bb = row0 / R, q0 = row0 - bb * R;
        u16x4 pk;
#pragma unroll
        for (int r = 0; r < 4; ++r) pk[r] = f2bf(acc[m][n][r] + bs);
        *reinterpret_cast<u16x4*>(Ct + ((size_t)(bb * 16 + hh) * 64 + dd) * R + q0) = pk;
      }
    } else {
#pragma unroll
      for (int m = 0; m < 4; ++m) {
        const int row0 = bm * 128 + wr + m * 16 + g * 4;
#pragma unroll
        for (int r = 0; r < 4; ++r) {
          float val = acc[m][n][r] + bs;
          size_t idx = (size_t)(row0 + r) * ldc + col;
          if (Cf) Cf[idx] = val;
          else    Cb[idx] = f2bf(val);
        }
      }
    }
  }
}

// ---------------------------------------------------------------- GEMM 288x256-tile, 8-phase schedule (R12)
// f32 epilogue now LDS-bounced (16B stores through the dead buffer).
template<int RT>
__global__ __launch_bounds__(512, 2) void gemm288(
    const bfu* __restrict__ A, const bfu* __restrict__ W, const float* __restrict__ bias,
    bfu* __restrict__ Cb, float* __restrict__ Cf, bfu* __restrict__ Ct, int colsplit,
    int ldc, int M, int N, int K, int nbn)
{
  __shared__ bfu lds[2 * 36864];      // 147456 B

  const int tid = threadIdx.x;
  const int w = tid >> 6, lane = tid & 63;
  const int g = lane >> 4, c = lane & 15;
  const int wr = w >> 2, wc = w & 3;
  const int rb0 = wr ? 208 : 0;
  const int rb1 = wr ? 144 : 80;

  const int nbm = M / 288;
  int bm, bn;
  { const int xcd = blockIdx.x & 7, j = blockIdx.x >> 3;
    const int jm = j / nbn; bm = xcd * (nbm >> 3) + jm; bn = j - jm * nbn; }

  const int nt = K >> 6;

  const int srow8 = lane >> 3;
  const int sslot = lane & 7;
  const int swzE  = ((sslot * 16) ^ (srow8 << 4)) >> 1;
  const bfu* srcA = A + (size_t)(bm * 288 + 8 * w + srow8) * K + swzE;
  const bfu* srcB = W + (size_t)(bn * 256 + 8 * w + srow8) * K + swzE;

#define AB(cur) (lds + (cur) * 36864)
#define BB(cur) (lds + (cur) * 36864 + 20480)
#define STAGE_A(cur, j, k0) gload_lds16(srcA + (size_t)(64 * (j)) * K + (k0), \
    (void*)(AB(cur) + (64 * (j) + 8 * w) * 64))
#define STAGE_B(cur, j, k0) gload_lds16(srcB + (size_t)(64 * (j)) * K + (k0), \
    (void*)(BB(cur) + (64 * (j) + 8 * w) * 64))

  short8 aF[5][2], bF[4][2];
  const int swzR = ((c & 7) << 3);

#define LDA(cur, mh, CNT) { _Pragma("unroll") for (int mi2 = 0; mi2 < (CNT); ++mi2) \
    _Pragma("unroll") for (int ks = 0; ks < 2; ++ks) \
      aF[mi2][ks] = *reinterpret_cast<const short8*>( \
        AB(cur) + (((mh) ? rb1 : rb0) + mi2 * 16 + c) * 64 + ((ks * 32 + g * 8) ^ swzR)); }
#define LDB(cur, nh) { _Pragma("unroll") for (int ni2 = 0; ni2 < 2; ++ni2) \
    _Pragma("unroll") for (int ks = 0; ks < 2; ++ks) \
      bF[(nh) * 2 + ni2][ks] = *reinterpret_cast<const short8*>( \
        BB(cur) + (wc * 64 + (nh) * 32 + ni2 * 16 + c) * 64 + ((ks * 32 + g * 8) ^ swzR)); }

  f32x4 acc[9][4];
  const f32x4 zero = {0.f, 0.f, 0.f, 0.f};
#pragma unroll
  for (int mi = 0; mi < 9; ++mi)
#pragma unroll
    for (int ni = 0; ni < 4; ++ni) acc[mi][ni] = zero;

#define PH_MFMA(mh, nh, CNT) { __builtin_amdgcn_s_setprio(1); \
    _Pragma("unroll") for (int mi2 = 0; mi2 < (CNT); ++mi2) \
    _Pragma("unroll") for (int ni2 = 0; ni2 < 2; ++ni2) \
    _Pragma("unroll") for (int ks = 0; ks < 2; ++ks) \
      acc[(mh) * 5 + mi2][(nh) * 2 + ni2] = \
        MFMA16(aF[mi2][ks], bF[(nh) * 2 + ni2][ks], acc[(mh) * 5 + mi2][(nh) * 2 + ni2]); \
    __builtin_amdgcn_s_setprio(0); }

  // ---- prologue
  STAGE_B(0, 0, 0); STAGE_B(0, 1, 0); STAGE_B(0, 2, 0); STAGE_B(0, 3, 0);
  STAGE_A(0, 0, 0); STAGE_A(0, 1, 0); STAGE_A(0, 3, 0); STAGE_A(0, 4, 0); STAGE_A(0, 2, 0);
  asm volatile("s_waitcnt vmcnt(0)" ::: "memory");
  __builtin_amdgcn_s_barrier();

  int cur = 0;
  for (int t = 0; t < nt - 1; ++t) {
    const int k1 = (t + 1) * 64;
    LDB(cur, 0); LDA(cur, 0, 5);
    STAGE_B(cur ^ 1, 0, k1); STAGE_B(cur ^ 1, 1, k1);
    STAGE_B(cur ^ 1, 2, k1); STAGE_B(cur ^ 1, 3, k1);
    __builtin_amdgcn_s_barrier();
    PH_MFMA(0, 0, 5);
    __builtin_amdgcn_s_barrier();
    LDB(cur, 1);
    STAGE_A(cur ^ 1, 0, k1); STAGE_A(cur ^ 1, 1, k1);
    STAGE_A(cur ^ 1, 3, k1); STAGE_A(cur ^ 1, 4, k1);
    asm volatile("s_waitcnt vmcnt(8)" ::: "memory");
    __builtin_amdgcn_s_barrier();
    PH_MFMA(0, 1, 5);
    __builtin_amdgcn_s_barrier();
    LDA(cur, 1, 4);
    STAGE_A(cur ^ 1, 2, k1);
    __builtin_amdgcn_s_barrier();
    PH_MFMA(1, 0, 4);
    __builtin_amdgcn_s_barrier();
    asm volatile("s_waitcnt vmcnt(1)" ::: "memory");
    __builtin_amdgcn_s_barrier();
    PH_MFMA(1, 1, 4);
    __builtin_amdgcn_s_barrier();
    cur ^= 1;
  }
  LDB(cur, 0); LDA(cur, 0, 5);
  __builtin_amdgcn_s_barrier();
  PH_MFMA(0, 0, 5);
  __builtin_amdgcn_s_barrier();
  LDB(cur, 1);
  asm volatile("s_waitcnt vmcnt(0)" ::: "memory");
  __builtin_amdgcn_s_barrier();
  PH_MFMA(0, 1, 5);
  __builtin_amdgcn_s_barrier();
  LDA(cur, 1, 4);
  PH_MFMA(1, 0, 4);
  PH_MFMA(1, 1, 4);

  // ---- epilogue (last tile used buf1 for nt even; buf0 dead -> bounce)
  const bool isCt = (RT > 0) && (bn * 256 >= colsplit);

  if (isCt) {
    const int RTl = (RT > 0 ? RT : 1);
    short* bw = (short*)lds + w * 2432;   // 16 x 152
#pragma unroll
    for (int ni = 0; ni < 4; ++ni) {
      const float bs = bias[bn * 256 + wc * 64 + ni * 16 + c];
#pragma unroll
      for (int mh = 0; mh < 2; ++mh)
#pragma unroll
        for (int mi2 = 0; mi2 < 5; ++mi2) {
          if (mh == 1 && mi2 == 4) continue;
          const int qlb = wr ? (mh ? 0 : 64) : (mh ? 80 : 0);
          u16x4 pk;
#pragma unroll
          for (int r = 0; r < 4; ++r) pk[r] = f2bf(acc[mh * 5 + mi2][ni][r] + bs);
          *reinterpret_cast<u16x4*>(&bw[c * 152 + qlb + mi2 * 16 + g * 4]) = pk;
        }
#pragma unroll
      for (int it = 0; it < 5; ++it) {
        const int idx = it * 64 + lane;
        if (idx < 288) {
          const int dd = idx / 18, q8 = idx - dd * 18;
          short8 vx = *reinterpret_cast<const short8*>(&bw[dd * 152 + q8 * 8]);
          const int colp = bn * 256 + wc * 64 + ni * 16 + dd - colsplit;
          const int hh = colp >> 6, dl = colp & 63;
          const int qg = bm * 288 + wr * 144 + q8 * 8;
          const int bb = qg / RTl, q0 = qg - bb * RTl;
          *reinterpret_cast<short8*>(Ct + ((size_t)(bb * 16 + hh) * 64 + dl) * RTl + q0) = vx;
        }
      }
    }
  } else if (Cf) {
    // f32 via LDS bounce: per m-tile 16 rows x 64 f32 (stride 68), 16B stores
    float* bwf = (float*)lds + w * 1088;
    float bs4[4];
#pragma unroll
    for (int ni = 0; ni < 4; ++ni) bs4[ni] = bias[bn * 256 + wc * 64 + ni * 16 + c];
#pragma unroll
    for (int mh = 0; mh < 2; ++mh)
#pragma unroll
      for (int mi2 = 0; mi2 < 5; ++mi2) {
        if (mh == 1 && mi2 == 4) continue;
#pragma unroll
        for (int ni = 0; ni < 4; ++ni)
#pragma unroll
          for (int r = 0; r < 4; ++r)
            bwf[(g * 4 + r) * 68 + ni * 16 + c] = acc[mh * 5 + mi2][ni][r] + bs4[ni];
#pragma unroll
        for (int p = 0; p < 4; ++p) {
          const int rr = lane >> 2;
          const int ch = p * 4 + (lane & 3);
          f32x4 vx = *reinterpret_cast<const f32x4*>(&bwf[rr * 68 + ch * 4]);
          const int row = bm * 288 + (mh ? rb1 : rb0) + mi2 * 16 + rr;
          *reinterpret_cast<f32x4*>(Cf + (size_t)row * ldc + bn * 256 + wc * 64 + ch * 4) = vx;
        }
      }
  } else {
    short* bw = (short*)lds + w * 1216;
    float bs4[4];
#pragma unroll
    for (int ni = 0; ni < 4; ++ni) bs4[ni] = bias[bn * 256 + wc * 64 + ni * 16 + c];
#pragma unroll
    for (int mh = 0; mh < 2; ++mh)
#pragma unroll
      for (int mi2 = 0; mi2 < 5; ++mi2) {
        if (mh == 1 && mi2 == 4) continue;
#pragma unroll
        for (int ni = 0; ni < 4; ++ni)
#pragma unroll
          for (int r = 0; r < 4; ++r)
            bw[(g * 4 + r) * 72 + ni * 16 + c] = (short)f2bf(acc[mh * 5 + mi2][ni][r] + bs4[ni]);
#pragma unroll
        for (int half = 0; half < 2; ++half) {
          const int rr = (lane >> 3) + half * 8;
          const int cc2 = (lane & 7) * 8;
          short8 vx = *reinterpret_cast<const short8*>(&bw[rr * 72 + cc2]);
          const int grow = bm * 288 + (mh ? rb1 : rb0) + mi2 * 16 + rr;
          *reinterpret_cast<short8*>(Cb + (size_t)grow * ldc + bn * 256 + wc * 64 + cc2) = vx;
        }
      }
  }
#undef AB
#undef BB
#undef STAGE_A
#undef STAGE_B
#undef LDA
#undef LDB
#undef PH_MFMA
}

// ---------------------------------------------------------------- swizzled per-wave P-tile offsets
__device__ __forceinline__ int pvt_off(int q, int kbyte) { return q * 256 + (kbyte ^ ((q & 7) << 4)); }

// ---------------------------------------------------------------- fused bidirectional attention, one block per (b,h)
// 4 waves x 9 iterations of 4 q-tiles. Per iter: S=QK^T -> P (LDS, per-wave swizzled tile)
// -> xv (own tile) ; barrier ; xl partial: wave w owns k-rows [32w,32w+32), A-frags gathered
// from all 4 P tiles, B from VVt ; barrier. No PT global round-trip, block-local colsum.
__global__ __launch_bounds__(256) void attn_bi(
    const bfu* __restrict__ Q, const bfu* __restrict__ Kl,
    const bfu* __restrict__ LVt, const bfu* __restrict__ VVt,
    const float* __restrict__ mask,
    bfu* __restrict__ xv, bfu* __restrict__ xl)
{
  __shared__ short Ks[128 * 64];      // 16 KB, swizzled
  __shared__ short LVs[64 * 128];     // 16 KB, swizzled within 128B half-rows
  __shared__ short PvT[4][2048];      // per-wave 16q x 128k P tile; reused as bounce buf
  __shared__ float cpart[4][128];

  const int bh = blockIdx.x;
  const int b = bh >> 4, h = bh & 15;
  const int t = threadIdx.x, l = t & 63, w = t >> 6;
  const int g = l >> 4, c = l & 15;

  const bfu* Qp  = Q   + ((size_t)b * 576 * 1024 + h * 64);
  const bfu* Kp  = Kl  + ((size_t)b * 128 * 1024 + h * 64);
  const bfu* LVp = LVt + (size_t)bh * 64 * 128;
  const bfu* VVp = VVt + (size_t)bh * 64 * 576;
  const f32x4 zero = {0.f, 0.f, 0.f, 0.f};

  // ---- stage K (128x64) and LV (64x128) into LDS, pre-swizzled global source
  {
    const int kr = l >> 3;
    const bfu* sK = Kp + (size_t)(w * 8 + kr) * 1024 + (((l & 7) ^ kr) * 8);
#pragma unroll
    for (int i = 0; i < 4; ++i)
      gload_lds16(sK + (size_t)(i * 32) * 1024, (void*)&Ks[(i * 32 + w * 8) * 64]);
    const int lr = l >> 4;
    const int key = (w * 4 + lr) & 7;
    const bfu* sLV = LVp + (size_t)(w * 4 + lr) * 128 + ((l >> 3) & 1) * 64 + (((l & 7) ^ key) * 8);
#pragma unroll
    for (int i = 0; i < 4; ++i)
      gload_lds16(sLV + (size_t)(i * 16) * 128, (void*)&LVs[(i * 16 + w * 4) * 128]);
  }
  float mk[8];
#pragma unroll
  for (int kt = 0; kt < 8; ++kt) mk[kt] = mask[kt * 16 + c];
  __syncthreads();

  char* myPv = (char*)&PvT[w][0];
  float colacc[8] = {0, 0, 0, 0, 0, 0, 0, 0};
  f32x4 xlacc[2][4];
#pragma unroll
  for (int kt2 = 0; kt2 < 2; ++kt2)
#pragma unroll
    for (int dt = 0; dt < 4; ++dt) xlacc[kt2][dt] = zero;

  for (int it = 0; it < 9; ++it) {
    const int qt = it * 4 + w;
    // ---- S = Q K^T (K from LDS)
    f32x4 sacc[8];
#pragma unroll
    for (int kt = 0; kt < 8; ++kt) sacc[kt] = zero;
    __builtin_amdgcn_s_setprio(1);
#pragma unroll
    for (int kk = 0; kk < 2; ++kk) {
      short8 aq = *reinterpret_cast<const short8*>(Qp + (size_t)(qt * 16 + c) * 1024 + kk * 32 + g * 8);
#pragma unroll
      for (int kt = 0; kt < 8; ++kt) {
        short8 bk = *reinterpret_cast<const short8*>(
            &Ks[(kt * 16 + c) * 64 + (((kk * 4 + g) ^ (c & 7)) * 8)]);
        sacc[kt] = MFMA16(aq, bk, sacc[kt]);
      }
    }
    __builtin_amdgcn_s_setprio(0);

    // ---- P = exp(S*scale + mask[k]) -> own LDS tile; rowsum + colsum
    float rs[4] = {0, 0, 0, 0};
#pragma unroll
    for (int kt = 0; kt < 8; ++kt) {
      float ca = 0.f;
#pragma unroll
      for (int r = 0; r < 4; ++r) {
        float Ev = __expf(fmaf(sacc[kt][r], SCALE_QK, mk[kt]));
        rs[r] += Ev;
        ca += Ev;
        *reinterpret_cast<unsigned short*>(myPv + pvt_off(g * 4 + r, 2 * (kt * 16 + c))) = f2bf(Ev);
      }
      colacc[kt] += ca;
    }
#pragma unroll
    for (int r = 0; r < 4; ++r) {
      rs[r] += __shfl_xor(rs[r], 1);
      rs[r] += __shfl_xor(rs[r], 2);
      rs[r] += __shfl_xor(rs[r], 4);
      rs[r] += __shfl_xor(rs[r], 8);
    }

    // ---- xv tile = P(16x128) @ LV(128x64) (own tile, LV from LDS)
    short8 av[4];
#pragma unroll
    for (int kc = 0; kc < 4; ++kc)
      av[kc] = *reinterpret_cast<const short8*>(myPv + pvt_off(c, kc * 64 + g * 16));
    f32x4 oxv[4];
#pragma unroll
    for (int dt = 0; dt < 4; ++dt) oxv[dt] = zero;
    __builtin_amdgcn_s_setprio(1);
#pragma unroll
    for (int dt = 0; dt < 4; ++dt)
#pragma unroll
      for (int kc = 0; kc < 4; ++kc) {
        short8 bv = *reinterpret_cast<const short8*>(
            &LVs[(dt * 16 + c) * 128 + (kc >> 1) * 64 + ((((kc & 1) * 4 + g) ^ (c & 7)) * 8)]);
        oxv[dt] = MFMA16(av[kc], bv, oxv[dt]);
      }
    __builtin_amdgcn_s_setprio(0);
#pragma unroll
    for (int r = 0; r < 4; ++r) rs[r] = 1.0f / rs[r];

    __syncthreads();   // all 4 P tiles of this iter ready

    // ---- xl partial: wave w owns k-rows [32w, 32w+32)
#pragma unroll
    for (int kt2 = 0; kt2 < 2; ++kt2) {
      const int kbyte = 2 * (w * 32 + kt2 * 16 + c);
      short8 ap[2];
#pragma unroll
      for (int ks = 0; ks < 2; ++ks) {
        const int wq = ks * 2 + (g >> 1);
        const int qb8 = (g & 1) * 8;
        const char* tile = (const char*)&PvT[wq][0];
#pragma unroll
        for (int j = 0; j < 8; ++j) {
          const int ql = qb8 + j;
          ap[ks][j] = *reinterpret_cast<const short*>(
              tile + ql * 256 + (kbyte ^ (j << 4)));
        }
      }
      __builtin_amdgcn_s_setprio(1);
#pragma unroll
      for (int dt = 0; dt < 4; ++dt) {
#pragma unroll
        for (int ks = 0; ks < 2; ++ks) {
          short8 bv = *reinterpret_cast<const short8*>(
              VVp + (size_t)(dt * 16 + c) * 576 + it * 64 + ks * 32 + g * 8);
          xlacc[kt2][dt] = MFMA16(ap[ks], bv, xlacc[kt2][dt]);
        }
      }
      __builtin_amdgcn_s_setprio(0);
    }
    __syncthreads();   // everyone done reading P tiles

    // ---- xv store via LDS bounce (own tile now safe to clobber)
    short* bw = (short*)&PvT[w][0];
#pragma unroll
    for (int dt = 0; dt < 4; ++dt)
#pragma unroll
      for (int r = 0; r < 4; ++r)
        bw[(g * 4 + r) * 72 + dt * 16 + c] = (short)f2bf(oxv[dt][r] * rs[r]);
#pragma unroll
    for (int half = 0; half < 2; ++half) {
      const int rr = (l >> 3) + half * 8;
      const int cc = (l & 7) * 8;
      short8 vx = *reinterpret_cast<const short8*>(&bw[rr * 72 + cc]);
      *reinterpret_cast<short8*>(xv + (size_t)(b * 576 + qt * 16 + rr) * 1024 + h * 64 + cc) = vx;
    }
  }

  // ---- block-local colsum
#pragma unroll
  for (int kt = 0; kt < 8; ++kt) {
    colacc[kt] += __shfl_xor(colacc[kt], 16);
    colacc[kt] += __shfl_xor(colacc[kt], 32);
  }
  if (g == 0) {
#pragma unroll
    for (int kt = 0; kt < 8; ++kt) cpart[w][kt * 16 + c] = colacc[kt];
  }
  __syncthreads();

  // ---- xl normalize + store (wave w: k-rows [32w, 32w+32))
  short* bw = (short*)&PvT[w][0];
#pragma unroll
  for (int kt2 = 0; kt2 < 2; ++kt2) {
    float ci[4];
#pragma unroll
    for (int r = 0; r < 4; ++r) {
      const int k = w * 32 + kt2 * 16 + g * 4 + r;
      ci[r] = 1.0f / (cpart[0][k] + cpart[1][k] + cpart[2][k] + cpart[3][k]);
    }
#pragma unroll
    for (int dt = 0; dt < 4; ++dt)
#pragma unroll
      for (int r = 0; r < 4; ++r)
        bw[(g * 4 + r) * 72 + dt * 16 + c] = (short)f2bf(xlacc[kt2][dt][r] * ci[r]);
#pragma unroll
    for (int half = 0; half < 2; ++half) {
      const int rr = (l >> 3) + half * 8;
      const int cc = (l & 7) * 8;
      short8 vx = *reinterpret_cast<const short8*>(&bw[rr * 72 + cc]);
      *reinterpret_cast<short8*>(xl + (size_t)(b * 128 + w * 32 + kt2 * 16 + rr) * 1024 + h * 64 + cc) = vx;
    }
  }
}

// ---------------------------------------------------------------- host
static inline int cvt_grid(int n4) {
  int g = (n4 + 255) / 256;
  return g > 4096 ? 4096 : g;
}

extern "C" void kernel_launch(void* const* d_in, const int* in_sizes, int n_in,
                              void* d_out, int out_size, void* d_ws, size_t ws_size,
                              hipStream_t stream)
{
  const float* v    = (const float*)d_in[0];
  const float* lx   = (const float*)d_in[1];
  const float* mask = (const float*)d_in[2];
  const float* Wvq  = (const float*)d_in[3];
  const float* bvq  = (const float*)d_in[4];
  const float* Wlk  = (const float*)d_in[5];
  const float* blk  = (const float*)d_in[6];
  const float* Wvv  = (const float*)d_in[7];
  const float* bvv  = (const float*)d_in[8];
  const float* Wlv  = (const float*)d_in[9];
  const float* blv  = (const float*)d_in[10];
  const float* Wvo  = (const float*)d_in[11];
  const float* bvo  = (const float*)d_in[12];
  const float* Wlo  = (const float*)d_in[13];
  const float* blo  = (const float*)d_in[14];

  float* out_xv = (float*)d_out;                       // 18432 x 1024
  float* out_xl = out_xv + (size_t)18432 * 1024;       // 4096 x 768

  bfu* ws   = (bfu*)d_ws;
  bfu* vb   = ws;                      // 18874368 (later aliased as xv bf16)
  bfu* lb   = vb   + 18874368;         // 3145728
  bfu* wqv  = lb   + 3145728;          // 2097152  [Wvq ; Wvv] (2048x1024)
  bfu* wklv = wqv  + 2097152;          // 1572864  [Wlk ; Wlv] (2048x768)
  bfu* wvo  = wklv + 1572864;          // 1048576
  bfu* wlo  = wvo  + 1048576;          // 786432
  bfu* Qb   = wlo  + 786432;           // 18874368  [18432][1024] bf16
  bfu* VVt  = Qb   + 18874368;         // 18874368  [bh][64][576]
  bfu* Kb   = VVt  + 18874368;         // 4194304   [4096][1024] (later aliased as xl bf16)
  bfu* LVt  = Kb   + 4194304;          // 4194304   [bh][64][128]
  float* biasqv = (float*)(LVt + 4194304);   // 2048 f32  [bvq ; bvv]
  float* biaskl = biasqv + 2048;             // 2048 f32  [blk ; blv]

  // 1) converts + bias concat
  cvt_f32_bf16<<<cvt_grid(18874368 / 4), 256, 0, stream>>>(v, vb, 18874368 / 4);
  CvtArgs ca;
  ca.src[0] = lx;  ca.dst[0] = lb;             ca.n4[0] = 3145728 / 4;
  ca.src[1] = Wvq; ca.dst[1] = wqv;            ca.n4[1] = 1048576 / 4;
  ca.src[2] = Wvv; ca.dst[2] = wqv + 1048576;  ca.n4[2] = 1048576 / 4;
  ca.src[3] = Wlk; ca.dst[3] = wklv;           ca.n4[3] = 786432 / 4;
  ca.src[4] = Wlv; ca.dst[4] = wklv + 786432;  ca.n4[4] = 786432 / 4;
  ca.src[5] = Wvo; ca.dst[5] = wvo;            ca.n4[5] = 1048576 / 4;
  ca.src[6] = Wlo; ca.dst[6] = wlo;            ca.n4[6] = 786432 / 4;
  cvt_multi<<<dim3(1024, 7), 256, 0, stream>>>(ca);
  bias_concat<<<4, 256, 0, stream>>>(bvq, bvv, blk, blv, biasqv, biaskl);

  // 2) projections: QV on 288x256 kernel (512 blocks = 2 exact rounds); KL on 128-tile kernel
  gemm288<576><<<64 * 8, 512, 0, stream>>>(vb, wqv, biasqv, Qb, nullptr, VVt, 1024, 1024,
                                           18432, 2048, 1024, 8);
  gemm_bt<<<32 * 16, 256, 0, stream>>>(lb, wklv, biaskl, Kb, nullptr, LVt, 128, 1024, 1024,
                                       4096, 2048, 768, 16);

  // 3) fused attention (xv -> vb alias, xl -> Kb alias); no PT round-trip
  attn_bi<<<512, 256, 0, stream>>>(Qb, Kb, LVt, VVt, mask, vb, Kb);

  // 4) output GEMMs: out_xv on 288x256 kernel (256 blocks = 1 exact round), out_xl on 128-tile
  gemm288<0><<<64 * 4, 512, 0, stream>>>(vb, wvo, bvo, nullptr, out_xv, nullptr, 1 << 30, 1024,
                                         18432, 1024, 1024, 4);
  gemm_bt<<<32 * 6, 256, 0, stream>>>(Kb, wlo, blo, nullptr, out_xl, nullptr, 0, 768, 768,
                                      4096, 768, 1024, 6);
}

// Round 14
// 256.443 us; speedup vs baseline: 1.3500x; 1.0003x over previous
//
#include <hip/hip_runtime.h>
#include <stdint.h>

// BiMultiHeadAttention (GLIP bi-attention), MI355X bf16 MFMA pipeline.
// B=32 VN=576 LN=128 E=1024 H=16 D=64, V_DIM=1024 L_DIM=768, SCALE=0.25.

typedef unsigned short bfu;   // bf16 storage
typedef __attribute__((ext_vector_type(4))) float f32x4;
typedef __attribute__((ext_vector_type(8))) short short8;
typedef __attribute__((ext_vector_type(4))) unsigned short u16x4;

#define MFMA16(a,b,c) __builtin_amdgcn_mfma_f32_16x16x32_bf16((a),(b),(c),0,0,0)
#define SCALE_QK 0.25f

__device__ __forceinline__ unsigned short f2bf(float x) {
  unsigned int u = __float_as_uint(x);
  u += 0x7fffu + ((u >> 16) & 1u);   // round-to-nearest-even
  return (unsigned short)(u >> 16);
}

__device__ __forceinline__ void gload_lds16(const void* g, void* l) {
  __builtin_amdgcn_global_load_lds(
      reinterpret_cast<__attribute__((address_space(1))) void*>(
          reinterpret_cast<uintptr_t>(g)),
      reinterpret_cast<__attribute__((address_space(3))) void*>(
          (uint32_t)reinterpret_cast<uintptr_t>(l)),
      16, 0, 0);
}

// ---------------------------------------------------------------- converts
__global__ void cvt_f32_bf16(const float* __restrict__ x, bfu* __restrict__ y, int n4) {
  for (int i = blockIdx.x * blockDim.x + threadIdx.x; i < n4; i += gridDim.x * blockDim.x) {
    const float4 f = *reinterpret_cast<const float4*>(x + (size_t)i * 4);
    u16x4 o;
    o[0] = f2bf(f.x); o[1] = f2bf(f.y); o[2] = f2bf(f.z); o[3] = f2bf(f.w);
    *reinterpret_cast<u16x4*>(y + (size_t)i * 4) = o;
  }
}

struct CvtArgs {
  const float* src[7];
  bfu* dst[7];
  int n4[7];
};

__global__ void cvt_multi(CvtArgs a) {
  const int s = blockIdx.y;
  const float* __restrict__ x = a.src[s];
  bfu* __restrict__ y = a.dst[s];
  const int n4 = a.n4[s];
  for (int i = blockIdx.x * blockDim.x + threadIdx.x; i < n4; i += gridDim.x * blockDim.x) {
    const float4 f = *reinterpret_cast<const float4*>(x + (size_t)i * 4);
    u16x4 o;
    o[0] = f2bf(f.x); o[1] = f2bf(f.y); o[2] = f2bf(f.z); o[3] = f2bf(f.w);
    *reinterpret_cast<u16x4*>(y + (size_t)i * 4) = o;
  }
}

// bias concat: one dispatch replaces 4 d2d memcpies
__global__ void bias_concat(const float* __restrict__ a, const float* __restrict__ b,
                            const float* __restrict__ c2, const float* __restrict__ d,
                            float* __restrict__ qv, float* __restrict__ kl) {
  const int i = threadIdx.x * 4;
  const float4* s;
  float* o;
  switch (blockIdx.x) {
    case 0: s = (const float4*)a;  o = qv;        break;
    case 1: s = (const float4*)b;  o = qv + 1024; break;
    case 2: s = (const float4*)c2; o = kl;        break;
    default: s = (const float4*)d; o = kl + 1024; break;
  }
  *reinterpret_cast<float4*>(o + i) = s[threadIdx.x];
}

// ---------------------------------------------------------------- GEMM 128-tile (m97 structure) — R5 version
__global__ __launch_bounds__(256) void gemm_bt(
    const bfu* __restrict__ A, const bfu* __restrict__ W, const float* __restrict__ bias,
    bfu* __restrict__ Cb, float* __restrict__ Cf, bfu* __restrict__ Ct, int R, int colsplit,
    int ldc, int M, int N, int K, int nbn)
{
  __shared__ bfu As[128 * 32];
  __shared__ bfu Bs[128 * 32];
  const int nbm = M >> 7;
  const int bid = blockIdx.x;
  int bm, bn;
  if ((nbm & 7) == 0) {             // bijective XCD-aware swizzle
    const int xcd = bid & 7, j = bid >> 3;
    const int jm = j / nbn;
    bm = xcd * (nbm >> 3) + jm;
    bn = j - jm * nbn;
  } else { bm = bid / nbn; bn = bid - (bid / nbn) * nbn; }

  const int t = threadIdx.x, l = t & 63, w = t >> 6;
  const int g = l >> 4, c = l & 15;
  const int wr = (w >> 1) * 64, wc = (w & 1) * 64;

  f32x4 zero = {0.f, 0.f, 0.f, 0.f};
  f32x4 acc[4][4];
  for (int m = 0; m < 4; ++m)
    for (int n = 0; n < 4; ++n) acc[m][n] = zero;

  const int rowA = l >> 2;
  const int kb   = (l & 3) * 16;

  for (int k0 = 0; k0 < K; k0 += 32) {
#pragma unroll
    for (int i = 0; i < 2; ++i) {
      int chunk = w * 2 + i;
      int r = chunk * 16 + rowA;
      const char* ga = (const char*)(A + (size_t)(bm * 128 + r) * K + k0) + kb;
      const char* gb = (const char*)(W + (size_t)(bn * 128 + r) * K + k0) + kb;
      gload_lds16(ga, (char*)As + chunk * 1024);
      gload_lds16(gb, (char*)Bs + chunk * 1024);
    }
    __syncthreads();
    short8 a[4], bf[4];
#pragma unroll
    for (int m = 0; m < 4; ++m)
      a[m] = *reinterpret_cast<const short8*>(&As[(wr + m * 16 + c) * 32 + g * 8]);
#pragma unroll
    for (int n = 0; n < 4; ++n)
      bf[n] = *reinterpret_cast<const short8*>(&Bs[(wc + n * 16 + c) * 32 + g * 8]);
#pragma unroll
    for (int m = 0; m < 4; ++m)
#pragma unroll
      for (int n = 0; n < 4; ++n)
        acc[m][n] = MFMA16(a[m], bf[n], acc[m][n]);
    __syncthreads();
  }

#pragma unroll
  for (int n = 0; n < 4; ++n) {
    const int col = bn * 128 + wc + n * 16 + c;
    const float bs = bias[col];
    if (col >= colsplit) {
      const int colp = col - colsplit;
      const int hh = colp >> 6, dd = colp & 63;
#pragma unroll
      for (int m = 0; m < 4; ++m) {
        const int row0 = bm * 128 + wr + m * 16 + g * 4;
        const int bb = row0 / R, q0 = row0 - bb * R;
        u16x4 pk;
#pragma unroll
        for (int r = 0; r < 4; ++r) pk[r] = f2bf(acc[m][n][r] + bs);
        *reinterpret_cast<u16x4*>(Ct + ((size_t)(bb * 16 + hh) * 64 + dd) * R + q0) = pk;
      }
    } else {
#pragma unroll
      for (int m = 0; m < 4; ++m) {
        const int row0 = bm * 128 + wr + m * 16 + g * 4;
#pragma unroll
        for (int r = 0; r < 4; ++r) {
          float val = acc[m][n][r] + bs;
          size_t idx = (size_t)(row0 + r) * ldc + col;
          if (Cf) Cf[idx] = val;
          else    Cb[idx] = f2bf(val);
        }
      }
    }
  }
}

// ---------------------------------------------------------------- GEMM 288x256-tile, 8-phase schedule (R12/R13)
template<int RT>
__global__ __launch_bounds__(512, 2) void gemm288(
    const bfu* __restrict__ A, const bfu* __restrict__ W, const float* __restrict__ bias,
    bfu* __restrict__ Cb, float* __restrict__ Cf, bfu* __restrict__ Ct, int colsplit,
    int ldc, int M, int N, int K, int nbn)
{
  __shared__ bfu lds[2 * 36864];      // 147456 B

  const int tid = threadIdx.x;
  const int w = tid >> 6, lane = tid & 63;
  const int g = lane >> 4, c = lane & 15;
  const int wr = w >> 2, wc = w & 3;
  const int rb0 = wr ? 208 : 0;
  const int rb1 = wr ? 144 : 80;

  const int nbm = M / 288;
  int bm, bn;
  { const int xcd = blockIdx.x & 7, j = blockIdx.x >> 3;
    const int jm = j / nbn; bm = xcd * (nbm >> 3) + jm; bn = j - jm * nbn; }

  const int nt = K >> 6;

  const int srow8 = lane >> 3;
  const int sslot = lane & 7;
  const int swzE  = ((sslot * 16) ^ (srow8 << 4)) >> 1;
  const bfu* srcA = A + (size_t)(bm * 288 + 8 * w + srow8) * K + swzE;
  const bfu* srcB = W + (size_t)(bn * 256 + 8 * w + srow8) * K + swzE;

#define AB(cur) (lds + (cur) * 36864)
#define BB(cur) (lds + (cur) * 36864 + 20480)
#define STAGE_A(cur, j, k0) gload_lds16(srcA + (size_t)(64 * (j)) * K + (k0), \
    (void*)(AB(cur) + (64 * (j) + 8 * w) * 64))
#define STAGE_B(cur, j, k0) gload_lds16(srcB + (size_t)(64 * (j)) * K + (k0), \
    (void*)(BB(cur) + (64 * (j) + 8 * w) * 64))

  short8 aF[5][2], bF[4][2];
  const int swzR = ((c & 7) << 3);

#define LDA(cur, mh, CNT) { _Pragma("unroll") for (int mi2 = 0; mi2 < (CNT); ++mi2) \
    _Pragma("unroll") for (int ks = 0; ks < 2; ++ks) \
      aF[mi2][ks] = *reinterpret_cast<const short8*>( \
        AB(cur) + (((mh) ? rb1 : rb0) + mi2 * 16 + c) * 64 + ((ks * 32 + g * 8) ^ swzR)); }
#define LDB(cur, nh) { _Pragma("unroll") for (int ni2 = 0; ni2 < 2; ++ni2) \
    _Pragma("unroll") for (int ks = 0; ks < 2; ++ks) \
      bF[(nh) * 2 + ni2][ks] = *reinterpret_cast<const short8*>( \
        BB(cur) + (wc * 64 + (nh) * 32 + ni2 * 16 + c) * 64 + ((ks * 32 + g * 8) ^ swzR)); }

  f32x4 acc[9][4];
  const f32x4 zero = {0.f, 0.f, 0.f, 0.f};
#pragma unroll
  for (int mi = 0; mi < 9; ++mi)
#pragma unroll
    for (int ni = 0; ni < 4; ++ni) acc[mi][ni] = zero;

#define PH_MFMA(mh, nh, CNT) { __builtin_amdgcn_s_setprio(1); \
    _Pragma("unroll") for (int mi2 = 0; mi2 < (CNT); ++mi2) \
    _Pragma("unroll") for (int ni2 = 0; ni2 < 2; ++ni2) \
    _Pragma("unroll") for (int ks = 0; ks < 2; ++ks) \
      acc[(mh) * 5 + mi2][(nh) * 2 + ni2] = \
        MFMA16(aF[mi2][ks], bF[(nh) * 2 + ni2][ks], acc[(mh) * 5 + mi2][(nh) * 2 + ni2]); \
    __builtin_amdgcn_s_setprio(0); }

  // ---- prologue
  STAGE_B(0, 0, 0); STAGE_B(0, 1, 0); STAGE_B(0, 2, 0); STAGE_B(0, 3, 0);
  STAGE_A(0, 0, 0); STAGE_A(0, 1, 0); STAGE_A(0, 3, 0); STAGE_A(0, 4, 0); STAGE_A(0, 2, 0);
  asm volatile("s_waitcnt vmcnt(0)" ::: "memory");
  __builtin_amdgcn_s_barrier();

  int cur = 0;
  for (int t = 0; t < nt - 1; ++t) {
    const int k1 = (t + 1) * 64;
    LDB(cur, 0); LDA(cur, 0, 5);
    STAGE_B(cur ^ 1, 0, k1); STAGE_B(cur ^ 1, 1, k1);
    STAGE_B(cur ^ 1, 2, k1); STAGE_B(cur ^ 1, 3, k1);
    __builtin_amdgcn_s_barrier();
    PH_MFMA(0, 0, 5);
    __builtin_amdgcn_s_barrier();
    LDB(cur, 1);
    STAGE_A(cur ^ 1, 0, k1); STAGE_A(cur ^ 1, 1, k1);
    STAGE_A(cur ^ 1, 3, k1); STAGE_A(cur ^ 1, 4, k1);
    asm volatile("s_waitcnt vmcnt(8)" ::: "memory");
    __builtin_amdgcn_s_barrier();
    PH_MFMA(0, 1, 5);
    __builtin_amdgcn_s_barrier();
    LDA(cur, 1, 4);
    STAGE_A(cur ^ 1, 2, k1);
    __builtin_amdgcn_s_barrier();
    PH_MFMA(1, 0, 4);
    __builtin_amdgcn_s_barrier();
    asm volatile("s_waitcnt vmcnt(1)" ::: "memory");
    __builtin_amdgcn_s_barrier();
    PH_MFMA(1, 1, 4);
    __builtin_amdgcn_s_barrier();
    cur ^= 1;
  }
  LDB(cur, 0); LDA(cur, 0, 5);
  __builtin_amdgcn_s_barrier();
  PH_MFMA(0, 0, 5);
  __builtin_amdgcn_s_barrier();
  LDB(cur, 1);
  asm volatile("s_waitcnt vmcnt(0)" ::: "memory");
  __builtin_amdgcn_s_barrier();
  PH_MFMA(0, 1, 5);
  __builtin_amdgcn_s_barrier();
  LDA(cur, 1, 4);
  PH_MFMA(1, 0, 4);
  PH_MFMA(1, 1, 4);

  // ---- epilogue (buf0 dead -> bounce)
  const bool isCt = (RT > 0) && (bn * 256 >= colsplit);

  if (isCt) {
    const int RTl = (RT > 0 ? RT : 1);
    short* bw = (short*)lds + w * 2432;   // 16 x 152
#pragma unroll
    for (int ni = 0; ni < 4; ++ni) {
      const float bs = bias[bn * 256 + wc * 64 + ni * 16 + c];
#pragma unroll
      for (int mh = 0; mh < 2; ++mh)
#pragma unroll
        for (int mi2 = 0; mi2 < 5; ++mi2) {
          if (mh == 1 && mi2 == 4) continue;
          const int qlb = wr ? (mh ? 0 : 64) : (mh ? 80 : 0);
          u16x4 pk;
#pragma unroll
          for (int r = 0; r < 4; ++r) pk[r] = f2bf(acc[mh * 5 + mi2][ni][r] + bs);
          *reinterpret_cast<u16x4*>(&bw[c * 152 + qlb + mi2 * 16 + g * 4]) = pk;
        }
#pragma unroll
      for (int it = 0; it < 5; ++it) {
        const int idx = it * 64 + lane;
        if (idx < 288) {
          const int dd = idx / 18, q8 = idx - dd * 18;
          short8 vx = *reinterpret_cast<const short8*>(&bw[dd * 152 + q8 * 8]);
          const int colp = bn * 256 + wc * 64 + ni * 16 + dd - colsplit;
          const int hh = colp >> 6, dl = colp & 63;
          const int qg = bm * 288 + wr * 144 + q8 * 8;
          const int bb = qg / RTl, q0 = qg - bb * RTl;
          *reinterpret_cast<short8*>(Ct + ((size_t)(bb * 16 + hh) * 64 + dl) * RTl + q0) = vx;
        }
      }
    }
  } else if (Cf) {
    float* bwf = (float*)lds + w * 1088;
    float bs4[4];
#pragma unroll
    for (int ni = 0; ni < 4; ++ni) bs4[ni] = bias[bn * 256 + wc * 64 + ni * 16 + c];
#pragma unroll
    for (int mh = 0; mh < 2; ++mh)
#pragma unroll
      for (int mi2 = 0; mi2 < 5; ++mi2) {
        if (mh == 1 && mi2 == 4) continue;
#pragma unroll
        for (int ni = 0; ni < 4; ++ni)
#pragma unroll
          for (int r = 0; r < 4; ++r)
            bwf[(g * 4 + r) * 68 + ni * 16 + c] = acc[mh * 5 + mi2][ni][r] + bs4[ni];
#pragma unroll
        for (int p = 0; p < 4; ++p) {
          const int rr = lane >> 2;
          const int ch = p * 4 + (lane & 3);
          f32x4 vx = *reinterpret_cast<const f32x4*>(&bwf[rr * 68 + ch * 4]);
          const int row = bm * 288 + (mh ? rb1 : rb0) + mi2 * 16 + rr;
          *reinterpret_cast<f32x4*>(Cf + (size_t)row * ldc + bn * 256 + wc * 64 + ch * 4) = vx;
        }
      }
  } else {
    short* bw = (short*)lds + w * 1216;
    float bs4[4];
#pragma unroll
    for (int ni = 0; ni < 4; ++ni) bs4[ni] = bias[bn * 256 + wc * 64 + ni * 16 + c];
#pragma unroll
    for (int mh = 0; mh < 2; ++mh)
#pragma unroll
      for (int mi2 = 0; mi2 < 5; ++mi2) {
        if (mh == 1 && mi2 == 4) continue;
#pragma unroll
        for (int ni = 0; ni < 4; ++ni)
#pragma unroll
          for (int r = 0; r < 4; ++r)
            bw[(g * 4 + r) * 72 + ni * 16 + c] = (short)f2bf(acc[mh * 5 + mi2][ni][r] + bs4[ni]);
#pragma unroll
        for (int half = 0; half < 2; ++half) {
          const int rr = (lane >> 3) + half * 8;
          const int cc2 = (lane & 7) * 8;
          short8 vx = *reinterpret_cast<const short8*>(&bw[rr * 72 + cc2]);
          const int grow = bm * 288 + (mh ? rb1 : rb0) + mi2 * 16 + rr;
          *reinterpret_cast<short8*>(Cb + (size_t)grow * ldc + bn * 256 + wc * 64 + cc2) = vx;
        }
      }
  }
#undef AB
#undef BB
#undef STAGE_A
#undef STAGE_B
#undef LDA
#undef LDB
#undef PH_MFMA
}

// ---------------------------------------------------------------- swizzled per-wave P-tile offsets
__device__ __forceinline__ int pvt_off(int q, int kbyte) { return q * 256 + (kbyte ^ ((q & 7) << 4)); }

// ---------------------------------------------------------------- fused bidirectional attention, one block per (b,h)
// R14: adds per-wave P^T tile (PkT, [k][q] 48B rows) so xl A-frags are 4 ds_read_b128
// instead of 32 scalar ds_read_u16 per iter per wave. xv store moved before barrier1.
__global__ __launch_bounds__(256) void attn_bi(
    const bfu* __restrict__ Q, const bfu* __restrict__ Kl,
    const bfu* __restrict__ LVt, const bfu* __restrict__ VVt,
    const float* __restrict__ mask,
    bfu* __restrict__ xv, bfu* __restrict__ xl)
{
  __shared__ short Ks[128 * 64];      // 16 KB, swizzled
  __shared__ short LVs[64 * 128];     // 16 KB, swizzled within 128B half-rows
  __shared__ short PvT[4][2048];      // per-wave 16q x 128k tile ([q][k] swizzled); also bounce buf
  __shared__ short PkT[4][128 * 24];  // per-wave 128k x 16q tile ([k][q], 48B rows) for xl A-frags
  __shared__ float cpart[4][128];

  const int bh = blockIdx.x;
  const int b = bh >> 4, h = bh & 15;
  const int t = threadIdx.x, l = t & 63, w = t >> 6;
  const int g = l >> 4, c = l & 15;

  const bfu* Qp  = Q   + ((size_t)b * 576 * 1024 + h * 64);
  const bfu* Kp  = Kl  + ((size_t)b * 128 * 1024 + h * 64);
  const bfu* LVp = LVt + (size_t)bh * 64 * 128;
  const bfu* VVp = VVt + (size_t)bh * 64 * 576;
  const f32x4 zero = {0.f, 0.f, 0.f, 0.f};

  // ---- stage K (128x64) and LV (64x128) into LDS, pre-swizzled global source
  {
    const int kr = l >> 3;
    const bfu* sK = Kp + (size_t)(w * 8 + kr) * 1024 + (((l & 7) ^ kr) * 8);
#pragma unroll
    for (int i = 0; i < 4; ++i)
      gload_lds16(sK + (size_t)(i * 32) * 1024, (void*)&Ks[(i * 32 + w * 8) * 64]);
    const int lr = l >> 4;
    const int key = (w * 4 + lr) & 7;
    const bfu* sLV = LVp + (size_t)(w * 4 + lr) * 128 + ((l >> 3) & 1) * 64 + (((l & 7) ^ key) * 8);
#pragma unroll
    for (int i = 0; i < 4; ++i)
      gload_lds16(sLV + (size_t)(i * 16) * 128, (void*)&LVs[(i * 16 + w * 4) * 128]);
  }
  float mk[8];
#pragma unroll
  for (int kt = 0; kt < 8; ++kt) mk[kt] = mask[kt * 16 + c];
  __syncthreads();

  char* myPv = (char*)&PvT[w][0];
  short* myPk = &PkT[w][0];
  float colacc[8] = {0, 0, 0, 0, 0, 0, 0, 0};
  f32x4 xlacc[2][4];
#pragma unroll
  for (int kt2 = 0; kt2 < 2; ++kt2)
#pragma unroll
    for (int dt = 0; dt < 4; ++dt) xlacc[kt2][dt] = zero;

  for (int it = 0; it < 9; ++it) {
    const int qt = it * 4 + w;
    // ---- S = Q K^T (K from LDS)
    f32x4 sacc[8];
#pragma unroll
    for (int kt = 0; kt < 8; ++kt) sacc[kt] = zero;
    __builtin_amdgcn_s_setprio(1);
#pragma unroll
    for (int kk = 0; kk < 2; ++kk) {
      short8 aq = *reinterpret_cast<const short8*>(Qp + (size_t)(qt * 16 + c) * 1024 + kk * 32 + g * 8);
#pragma unroll
      for (int kt = 0; kt < 8; ++kt) {
        short8 bk = *reinterpret_cast<const short8*>(
            &Ks[(kt * 16 + c) * 64 + (((kk * 4 + g) ^ (c & 7)) * 8)]);
        sacc[kt] = MFMA16(aq, bk, sacc[kt]);
      }
    }
    __builtin_amdgcn_s_setprio(0);

    // ---- P = exp(S*scale + mask[k]) -> PvT ([q][k], for xv) + PkT ([k][q], for xl)
    float rs[4] = {0, 0, 0, 0};
#pragma unroll
    for (int kt = 0; kt < 8; ++kt) {
      float ca = 0.f;
      u16x4 pk;
#pragma unroll
      for (int r = 0; r < 4; ++r) {
        float Ev = __expf(fmaf(sacc[kt][r], SCALE_QK, mk[kt]));
        rs[r] += Ev;
        ca += Ev;
        pk[r] = f2bf(Ev);
        *reinterpret_cast<unsigned short*>(myPv + pvt_off(g * 4 + r, 2 * (kt * 16 + c))) = pk[r];
      }
      colacc[kt] += ca;
      *reinterpret_cast<u16x4*>(&myPk[(kt * 16 + c) * 24 + g * 4]) = pk;
    }
#pragma unroll
    for (int r = 0; r < 4; ++r) {
      rs[r] += __shfl_xor(rs[r], 1);
      rs[r] += __shfl_xor(rs[r], 2);
      rs[r] += __shfl_xor(rs[r], 4);
      rs[r] += __shfl_xor(rs[r], 8);
    }

    // ---- xv tile = P(16x128) @ LV(128x64) (own PvT tile, LV from LDS)
    short8 av[4];
#pragma unroll
    for (int kc = 0; kc < 4; ++kc)
      av[kc] = *reinterpret_cast<const short8*>(myPv + pvt_off(c, kc * 64 + g * 16));
    f32x4 oxv[4];
#pragma unroll
    for (int dt = 0; dt < 4; ++dt) oxv[dt] = zero;
    __builtin_amdgcn_s_setprio(1);
#pragma unroll
    for (int dt = 0; dt < 4; ++dt)
#pragma unroll
      for (int kc = 0; kc < 4; ++kc) {
        short8 bv = *reinterpret_cast<const short8*>(
            &LVs[(dt * 16 + c) * 128 + (kc >> 1) * 64 + ((((kc & 1) * 4 + g) ^ (c & 7)) * 8)]);
        oxv[dt] = MFMA16(av[kc], bv, oxv[dt]);
      }
    __builtin_amdgcn_s_setprio(0);
#pragma unroll
    for (int r = 0; r < 4; ++r) rs[r] = 1.0f / rs[r];

    // ---- xv store via LDS bounce (own PvT tile; no cross-wave readers of PvT)
    {
      short* bw = (short*)&PvT[w][0];
#pragma unroll
      for (int dt = 0; dt < 4; ++dt)
#pragma unroll
        for (int r = 0; r < 4; ++r)
          bw[(g * 4 + r) * 72 + dt * 16 + c] = (short)f2bf(oxv[dt][r] * rs[r]);
#pragma unroll
      for (int half = 0; half < 2; ++half) {
        const int rr = (l >> 3) + half * 8;
        const int cc = (l & 7) * 8;
        short8 vx = *reinterpret_cast<const short8*>(&bw[rr * 72 + cc]);
        *reinterpret_cast<short8*>(xv + (size_t)(b * 576 + qt * 16 + rr) * 1024 + h * 64 + cc) = vx;
      }
    }

    __syncthreads();   // all 4 PkT tiles of this iter ready

    // ---- xl partial: wave w owns k-rows [32w, 32w+32); A-frags = b128 reads from PkT
#pragma unroll
    for (int kt2 = 0; kt2 < 2; ++kt2) {
      const int krow = w * 32 + kt2 * 16 + c;
      short8 ap[2];
#pragma unroll
      for (int ks = 0; ks < 2; ++ks) {
        const int wq = ks * 2 + (g >> 1);
        ap[ks] = *reinterpret_cast<const short8*>(&PkT[wq][krow * 24 + (g & 1) * 8]);
      }
      __builtin_amdgcn_s_setprio(1);
#pragma unroll
      for (int dt = 0; dt < 4; ++dt) {
#pragma unroll
        for (int ks = 0; ks < 2; ++ks) {
          short8 bv = *reinterpret_cast<const short8*>(
              VVp + (size_t)(dt * 16 + c) * 576 + it * 64 + ks * 32 + g * 8);
          xlacc[kt2][dt] = MFMA16(ap[ks], bv, xlacc[kt2][dt]);
        }
      }
      __builtin_amdgcn_s_setprio(0);
    }
    __syncthreads();   // everyone done reading PkT before next iter overwrites
  }

  // ---- block-local colsum
#pragma unroll
  for (int kt = 0; kt < 8; ++kt) {
    colacc[kt] += __shfl_xor(colacc[kt], 16);
    colacc[kt] += __shfl_xor(colacc[kt], 32);
  }
  if (g == 0) {
#pragma unroll
    for (int kt = 0; kt < 8; ++kt) cpart[w][kt * 16 + c] = colacc[kt];
  }
  __syncthreads();

  // ---- xl normalize + store (wave w: k-rows [32w, 32w+32))
  short* bw = (short*)&PvT[w][0];
#pragma unroll
  for (int kt2 = 0; kt2 < 2; ++kt2) {
    float ci[4];
#pragma unroll
    for (int r = 0; r < 4; ++r) {
      const int k = w * 32 + kt2 * 16 + g * 4 + r;
      ci[r] = 1.0f / (cpart[0][k] + cpart[1][k] + cpart[2][k] + cpart[3][k]);
    }
#pragma unroll
    for (int dt = 0; dt < 4; ++dt)
#pragma unroll
      for (int r = 0; r < 4; ++r)
        bw[(g * 4 + r) * 72 + dt * 16 + c] = (short)f2bf(xlacc[kt2][dt][r] * ci[r]);
#pragma unroll
    for (int half = 0; half < 2; ++half) {
      const int rr = (l >> 3) + half * 8;
      const int cc = (l & 7) * 8;
      short8 vx = *reinterpret_cast<const short8*>(&bw[rr * 72 + cc]);
      *reinterpret_cast<short8*>(xl + (size_t)(b * 128 + w * 32 + kt2 * 16 + rr) * 1024 + h * 64 + cc) = vx;
    }
  }
}

// ---------------------------------------------------------------- host
static inline int cvt_grid(int n4) {
  int g = (n4 + 255) / 256;
  return g > 4096 ? 4096 : g;
}

extern "C" void kernel_launch(void* const* d_in, const int* in_sizes, int n_in,
                              void* d_out, int out_size, void* d_ws, size_t ws_size,
                              hipStream_t stream)
{
  const float* v    = (const float*)d_in[0];
  const float* lx   = (const float*)d_in[1];
  const float* mask = (const float*)d_in[2];
  const float* Wvq  = (const float*)d_in[3];
  const float* bvq  = (const float*)d_in[4];
  const float* Wlk  = (const float*)d_in[5];
  const float* blk  = (const float*)d_in[6];
  const float* Wvv  = (const float*)d_in[7];
  const float* bvv  = (const float*)d_in[8];
  const float* Wlv  = (const float*)d_in[9];
  const float* blv  = (const float*)d_in[10];
  const float* Wvo  = (const float*)d_in[11];
  const float* bvo  = (const float*)d_in[12];
  const float* Wlo  = (const float*)d_in[13];
  const float* blo  = (const float*)d_in[14];

  float* out_xv = (float*)d_out;                       // 18432 x 1024
  float* out_xl = out_xv + (size_t)18432 * 1024;       // 4096 x 768

  bfu* ws   = (bfu*)d_ws;
  bfu* vb   = ws;                      // 18874368 (later aliased as xv bf16)
  bfu* lb   = vb   + 18874368;         // 3145728
  bfu* wqv  = lb   + 3145728;          // 2097152  [Wvq ; Wvv] (2048x1024)
  bfu* wklv = wqv  + 2097152;          // 1572864  [Wlk ; Wlv] (2048x768)
  bfu* wvo  = wklv + 1572864;          // 1048576
  bfu* wlo  = wvo  + 1048576;          // 786432
  bfu* Qb   = wlo  + 786432;           // 18874368  [18432][1024] bf16
  bfu* VVt  = Qb   + 18874368;         // 18874368  [bh][64][576]
  bfu* Kb   = VVt  + 18874368;         // 4194304   [4096][1024] (later aliased as xl bf16)
  bfu* LVt  = Kb   + 4194304;          // 4194304   [bh][64][128]
  float* biasqv = (float*)(LVt + 4194304);   // 2048 f32  [bvq ; bvv]
  float* biaskl = biasqv + 2048;             // 2048 f32  [blk ; blv]

  // 1) converts + bias concat
  cvt_f32_bf16<<<cvt_grid(18874368 / 4), 256, 0, stream>>>(v, vb, 18874368 / 4);
  CvtArgs ca;
  ca.src[0] = lx;  ca.dst[0] = lb;             ca.n4[0] = 3145728 / 4;
  ca.src[1] = Wvq; ca.dst[1] = wqv;            ca.n4[1] = 1048576 / 4;
  ca.src[2] = Wvv; ca.dst[2] = wqv + 1048576;  ca.n4[2] = 1048576 / 4;
  ca.src[3] = Wlk; ca.dst[3] = wklv;           ca.n4[3] = 786432 / 4;
  ca.src[4] = Wlv; ca.dst[4] = wklv + 786432;  ca.n4[4] = 786432 / 4;
  ca.src[5] = Wvo; ca.dst[5] = wvo;            ca.n4[5] = 1048576 / 4;
  ca.src[6] = Wlo; ca.dst[6] = wlo;            ca.n4[6] = 786432 / 4;
  cvt_multi<<<dim3(1024, 7), 256, 0, stream>>>(ca);
  bias_concat<<<4, 256, 0, stream>>>(bvq, bvv, blk, blv, biasqv, biaskl);

  // 2) projections: QV on 288x256 kernel (512 blocks = 2 exact rounds); KL on 128-tile kernel
  gemm288<576><<<64 * 8, 512, 0, stream>>>(vb, wqv, biasqv, Qb, nullptr, VVt, 1024, 1024,
                                           18432, 2048, 1024, 8);
  gemm_bt<<<32 * 16, 256, 0, stream>>>(lb, wklv, biaskl, Kb, nullptr, LVt, 128, 1024, 1024,
                                       4096, 2048, 768, 16);

  // 3) fused attention (xv -> vb alias, xl -> Kb alias)
  attn_bi<<<512, 256, 0, stream>>>(Qb, Kb, LVt, VVt, mask, vb, Kb);

  // 4) output GEMMs: out_xv on 288x256 kernel (256 blocks = 1 exact round), out_xl on 128-tile
  gemm288<0><<<64 * 4, 512, 0, stream>>>(vb, wvo, bvo, nullptr, out_xv, nullptr, 1 << 30, 1024,
                                         18432, 1024, 1024, 4);
  gemm_bt<<<32 * 6, 256, 0, stream>>>(Kb, wlo, blo, nullptr, out_xl, nullptr, 0, 768, 768,
                                      4096, 768, 1024, 6);
}